// Round 4
// baseline (4511.482 us; speedup 1.0000x reference)
//
#include <hip/hip_runtime.h>

#define BB 16
#define KD 1024
#define DD 768
#define SS 384
#define HH 192
#define NBLK 64

// ================= common 128x128xBK16 fp32 GEMM micro-core =================
// 256 threads, 8x8 acc per thread, rows {ty*4, 64+ty*4}, cols {tx*4, 64+tx*4}.
// All LDS reads <=2-way bank aliasing (free on CDNA4).
__device__ __forceinline__ void mac16(float (&acc)[8][8], const float (*As)[132], const float (*Bs)[132],
                                      int ty, int tx) {
#pragma unroll
    for (int kk = 0; kk < 16; kk++) {
        float a[8], b[8];
        *(float4*)&a[0] = *(const float4*)&As[kk][ty * 4];
        *(float4*)&a[4] = *(const float4*)&As[kk][64 + ty * 4];
        *(float4*)&b[0] = *(const float4*)&Bs[kk][tx * 4];
        *(float4*)&b[4] = *(const float4*)&Bs[kk][64 + tx * 4];
#pragma unroll
        for (int i = 0; i < 8; i++)
#pragma unroll
            for (int j = 0; j < 8; j++)
                acc[i][j] += a[i] * b[j];
    }
}

// transpose-store an A-style tile (row-major MxK source chunk) into As[k][m]
__device__ __forceinline__ void storeA_t(float (*As)[132], const float4& v0, const float4& v1,
                                         int la_r, int la_c) {
    As[la_c + 0][la_r] = v0.x; As[la_c + 1][la_r] = v0.y;
    As[la_c + 2][la_r] = v0.z; As[la_c + 3][la_r] = v0.w;
    As[la_c + 0][64 + la_r] = v1.x; As[la_c + 1][64 + la_r] = v1.y;
    As[la_c + 2][64 + la_r] = v1.z; As[la_c + 3][64 + la_r] = v1.w;
}

// ---------- split x into e_i / d_i ----------
__global__ void k_prep(const float* __restrict__ x, float* __restrict__ di, float* __restrict__ ei) {
    int idx = blockIdx.x * 256 + threadIdx.x;       // over BB*KD*SS
    int s = idx % SS;
    long bk = idx / SS;
    const float* xr = x + bk * DD;
    ei[idx] = xr[s < HH ? s : s + HH];
    di[idx] = xr[s < HH ? s + HH : s + 2 * HH];
}

// ---------- generic fp32 NN GEMM: C[M,N] = act(A[M,Kd] @ B[Kd,N] + bias) ----------
template<bool BIAS, bool TANH>
__global__ __launch_bounds__(256, 2)
void k_gemm16(const float* __restrict__ A, const float* __restrict__ Bw,
              const float* __restrict__ bias, float* __restrict__ C,
              int M, int N, int Kd) {
    __shared__ float As[16][132];
    __shared__ float Bs[16][132];
    int m0 = blockIdx.x * 128, n0 = blockIdx.y * 128;
    int t = threadIdx.x;
    int ty = t / 16, tx = t % 16;
    int la_r = t / 4, la_c = (t % 4) * 4;
    int lb_r = t / 16, lb_c = (t % 16) * 4;
    float acc[8][8] = {};
    for (int k0 = 0; k0 < Kd; k0 += 16) {
        float4 a0 = *(const float4*)&A[(long)(m0 + la_r) * Kd + k0 + la_c];
        float4 a1 = *(const float4*)&A[(long)(m0 + 64 + la_r) * Kd + k0 + la_c];
        float4 b0 = *(const float4*)&Bw[(long)(k0 + lb_r) * N + n0 + lb_c];
        float4 b1 = *(const float4*)&Bw[(long)(k0 + lb_r) * N + n0 + 64 + lb_c];
        __syncthreads();
        storeA_t(As, a0, a1, la_r, la_c);
        *(float4*)&Bs[lb_r][lb_c] = b0;
        *(float4*)&Bs[lb_r][64 + lb_c] = b1;
        __syncthreads();
        mac16(acc, As, Bs, ty, tx);
    }
#pragma unroll
    for (int i = 0; i < 8; i++) {
        int row = m0 + (i < 4 ? ty * 4 + i : 64 + ty * 4 + i - 4);
        float4 o0, o1;
        float* p0 = &o0.x; float* p1 = &o1.x;
#pragma unroll
        for (int j = 0; j < 4; j++) {
            float v = acc[i][j];
            if (BIAS) v += bias[n0 + tx * 4 + j];
            if (TANH) v = tanhf(v);
            p0[j] = v;
            float w = acc[i][j + 4];
            if (BIAS) w += bias[n0 + 64 + tx * 4 + j];
            if (TANH) w = tanhf(w);
            p1[j] = w;
        }
        *(float4*)&C[(long)row * N + n0 + tx * 4] = o0;
        *(float4*)&C[(long)row * N + n0 + 64 + tx * 4] = o1;
    }
}

// ---------- merged parent/child transforms: uj = tanh(di@Wp+bp), uk = tanh(di@Wc+bc) ----------
// grid (128, 6): y<3 -> {Wp,bp,uj}, else {Wc,bc,uk}. Same A tiles, one launch.
__global__ __launch_bounds__(256, 2)
void k_gemm_pc(const float* __restrict__ A, const float* __restrict__ Wp,
               const float* __restrict__ bp, const float* __restrict__ Wc,
               const float* __restrict__ bc, float* __restrict__ Uj, float* __restrict__ Uk) {
    __shared__ float As[16][132];
    __shared__ float Bs[16][132];
    bool first = blockIdx.y < 3;
    const float* Bw = first ? Wp : Wc;
    const float* bias = first ? bp : bc;
    float* C = first ? Uj : Uk;
    int m0 = blockIdx.x * 128, n0 = (blockIdx.y % 3) * 128;
    int t = threadIdx.x;
    int ty = t / 16, tx = t % 16;
    int la_r = t / 4, la_c = (t % 4) * 4;
    int lb_r = t / 16, lb_c = (t % 16) * 4;
    float acc[8][8] = {};
    for (int k0 = 0; k0 < SS; k0 += 16) {
        float4 a0 = *(const float4*)&A[(long)(m0 + la_r) * SS + k0 + la_c];
        float4 a1 = *(const float4*)&A[(long)(m0 + 64 + la_r) * SS + k0 + la_c];
        float4 b0 = *(const float4*)&Bw[(long)(k0 + lb_r) * SS + n0 + lb_c];
        float4 b1 = *(const float4*)&Bw[(long)(k0 + lb_r) * SS + n0 + 64 + lb_c];
        __syncthreads();
        storeA_t(As, a0, a1, la_r, la_c);
        *(float4*)&Bs[lb_r][lb_c] = b0;
        *(float4*)&Bs[lb_r][64 + lb_c] = b1;
        __syncthreads();
        mac16(acc, As, Bs, ty, tx);
    }
#pragma unroll
    for (int i = 0; i < 8; i++) {
        int row = m0 + (i < 4 ? ty * 4 + i : 64 + ty * 4 + i - 4);
        float4 o0, o1;
        float* p0 = &o0.x; float* p1 = &o1.x;
#pragma unroll
        for (int j = 0; j < 4; j++) {
            p0[j] = tanhf(acc[i][j] + bias[n0 + tx * 4 + j]);
            p1[j] = tanhf(acc[i][j + 4] + bias[n0 + 64 + tx * 4 + j]);
        }
        *(float4*)&C[(long)row * SS + n0 + tx * 4] = o0;
        *(float4*)&C[(long)row * SS + n0 + 64 + tx * 4] = o1;
    }
}

// ---------- batched NT GEMM: S[b,j,k] = sum_s T[b,j,s]*Uk[b,k,s]  (raw scores) ----------
__global__ __launch_bounds__(256, 2)
void k_fjk16(const float* __restrict__ T, const float* __restrict__ Uk, float* __restrict__ Sout) {
    __shared__ float As[16][132];
    __shared__ float Bs[16][132];
    int b = blockIdx.z;
    const float* Ab = T + (long)b * KD * SS;
    const float* Bb = Uk + (long)b * KD * SS;
    int m0 = blockIdx.x * 128, n0 = blockIdx.y * 128;
    int t = threadIdx.x;
    int ty = t / 16, tx = t % 16;
    int la_r = t / 4, la_c = (t % 4) * 4;
    float acc[8][8] = {};
    for (int k0 = 0; k0 < SS; k0 += 16) {
        float4 a0 = *(const float4*)&Ab[(long)(m0 + la_r) * SS + k0 + la_c];
        float4 a1 = *(const float4*)&Ab[(long)(m0 + 64 + la_r) * SS + k0 + la_c];
        float4 b0 = *(const float4*)&Bb[(long)(n0 + la_r) * SS + k0 + la_c];
        float4 b1 = *(const float4*)&Bb[(long)(n0 + 64 + la_r) * SS + k0 + la_c];
        __syncthreads();
        storeA_t(As, a0, a1, la_r, la_c);
        storeA_t(Bs, b0, b1, la_r, la_c);
        __syncthreads();
        mac16(acc, As, Bs, ty, tx);
    }
#pragma unroll
    for (int i = 0; i < 8; i++) {
        int row = m0 + (i < 4 ? ty * 4 + i : 64 + ty * 4 + i - 4);
        *(float4*)&Sout[((long)b * KD + row) * KD + n0 + tx * 4] = *(float4*)&acc[i][0];
        *(float4*)&Sout[((long)b * KD + row) * KD + n0 + 64 + tx * 4] = *(float4*)&acc[i][4];
    }
}

// ---------- raw root logit g = d_i . fi_w ----------
__global__ void k_firaw(const float* __restrict__ di, const float* __restrict__ fiw, float* __restrict__ g) {
    int w = (blockIdx.x * 256 + threadIdx.x) / 64;
    int lane = threadIdx.x % 64;
    if (w >= BB * KD) return;
    const float* dr = di + (long)w * SS;
    float s = 0.f;
    for (int i = lane; i < SS; i += 64) s += dr[i] * fiw[i];
    for (int off = 32; off; off >>= 1) s += __shfl_down(s, off);
    if (lane == 0) g[w] = s;
}

// ---------- per-column max, stage 1: partial over 64-row j-chunks ----------
__global__ void k_colmax1(const float* __restrict__ S, float* __restrict__ pmax) {
    int idx = blockIdx.x * 256 + threadIdx.x;   // BB*KD
    int jt = blockIdx.y;                        // 16 j-chunks of 64
    int b = idx >> 10, k = idx & (KD - 1);
    const float* Sb = S + (long)b * KD * KD;
    float m = -3.4e38f;
    for (int j = jt * 64; j < jt * 64 + 64; j++) {
        float v = Sb[(long)j * KD + k];
        m = fmaxf(m, (j == k) ? -3.4e38f : v);
    }
    pmax[((long)jt << 14) + idx] = m;
}

// ---------- per-column max, stage 2: reduce partials + fold g; fi = exp(g-m); zero csd ----------
__global__ void k_colmax2(const float* __restrict__ pmax, const float* __restrict__ g,
                          float* __restrict__ mcol, float* __restrict__ fi, double* __restrict__ csd) {
    int idx = blockIdx.x * 256 + threadIdx.x;   // BB*KD
    float gv = g[idx];
    float m = gv;
    for (int jt = 0; jt < 16; jt++) m = fmaxf(m, pmax[((long)jt << 14) + idx]);
    mcol[idx] = m;
    fi[idx] = expf(gv - m);
    csd[idx] = 0.0;                             // prepare for fused col-sum atomics
}

// ---------- A = exp(S - m_col) (diag zeroed, in place) + fused fp64 column sums ----------
// 64x64 tile per block; per-column partial reduced in LDS, one atomicAdd per col per j-tile.
__global__ __launch_bounds__(256)
void k_expA_sum(float* __restrict__ S, const float* __restrict__ mcol, double* __restrict__ csd) {
    __shared__ double red[4][64];
    int b = blockIdx.z, jt = blockIdx.y, kt = blockIdx.x;
    int t = threadIdx.x;
    int tc = t & 63, tg = t >> 6;               // col in tile, row-group (4x16 rows)
    int kg = kt * 64 + tc;
    float mc = mcol[(b << 10) + kg];
    float* Sb = S + ((long)b << 20);
    double s = 0.0;
    for (int rr = 0; rr < 16; rr++) {
        int j = jt * 64 + tg * 16 + rr;
        long a = ((long)j << 10) + kg;
        float v = (j == kg) ? 0.f : expf(Sb[a] - mc);
        Sb[a] = v;
        s += (double)v;
    }
    red[tg][tc] = s;
    __syncthreads();
    if (tg == 0) {
        double tot = red[0][tc] + red[1][tc] + red[2][tc] + red[3][tc];
        atomicAdd(&csd[(b << 10) + kg], tot);
    }
}

// ---------- build padded T~ (fp64): T[i][j] = L[1+i][1+j] for i,j<1023; identity pad at 1023 ----------
__global__ void k_buildT(const float* __restrict__ A, const double* __restrict__ csd, double* __restrict__ Td) {
    long idx = (long)blockIdx.x * 256 + threadIdx.x;  // BB*KD*KD
    int j = idx & (KD - 1);
    int i = (int)(idx >> 10) & (KD - 1);
    int b = (int)(idx >> 20);
    double v;
    if (i == KD - 1 || j == KD - 1) v = (i == j) ? 1.0 : 0.0;
    else if (i == j) v = csd[(b << 10) + j + 1];
    else v = -(double)A[((long)b << 20) + ((long)(i + 1) << 10) + (j + 1)];
    Td[idx] = v;
}

// ---------- GJ step (fp64): fused {savecol || diag} ----------
// savecol blocks copy the pivot-column block M[:, kb:kb+64] to Ft; diag blocks
// invert the 64x64 diagonal block in LDS. Independent: diag writes only rows
// kb..kb+63 of the pivot column, and those Ft rows (it==kt) are skipped by
// k_elim_d, so concurrent/torn reads of that sub-block are never consumed.
__global__ __launch_bounds__(256)
void k_diagsave_d(double* __restrict__ M, double* __restrict__ Ft, int kb) {
    __shared__ double P[NBLK][NBLK + 1];
    __shared__ double rowbuf[NBLK];
    const int nsave = BB * KD * NBLK / 256;   // 4096 copy blocks
    if ((int)blockIdx.x < nsave) {
        int idx = blockIdx.x * 256 + threadIdx.x;     // BB*KD*NBLK
        int c = idx % NBLK;
        int rk = idx / NBLK;
        int r = rk % KD, b = rk / KD;
        Ft[idx] = M[((long)b * KD + r) * KD + kb + c];
        return;
    }
    int b = blockIdx.x - nsave;
    double* Mb = M + (long)b * KD * KD;
    int t = threadIdx.x;
    for (int i = t; i < NBLK * NBLK; i += 256)
        P[i / NBLK][i % NBLK] = Mb[(long)(kb + i / NBLK) * KD + kb + i % NBLK];
    __syncthreads();
    int mi = t & 63;
    int c0 = (t >> 6) * 16;
    for (int kk = 0; kk < NBLK; kk++) {
        double p = 1.0 / P[kk][kk];
        double F = P[mi][kk];
        if (t < 64) rowbuf[t] = P[kk][t] * p;
        __syncthreads();
        if (mi == kk) {
            for (int c = c0; c < c0 + 16; c++)
                P[mi][c] = (c == kk) ? p : rowbuf[c];
        } else {
            for (int c = c0; c < c0 + 16; c++)
                P[mi][c] = (c == kk) ? (-F * p) : (P[mi][c] - F * rowbuf[c]);
        }
        __syncthreads();
    }
    for (int i = t; i < NBLK * NBLK; i += 256)
        Mb[(long)(kb + i / NBLK) * KD + kb + i % NBLK] = P[i / NBLK][i % NBLK];
}

// ---------- GJ step (fp64): pivot block-row update  M[k, strip] = Dinv @ M[k, strip] ----------
// 32-col strips, self-contained: each block reads the Dinv diagonal tile (read-only
// here) + its own 64x32 pivot-row strip into LDS, then overwrites the same strip.
// No cross-block hazard. grid (30, BB).
__global__ __launch_bounds__(256)
void k_rowcol_d(double* __restrict__ M, int kb) {
    __shared__ double Ps[NBLK][NBLK + 1];   // Dinv[r][k]
    __shared__ double Ts[NBLK][33];         // R[k][c] (32-col strip)
    int b = blockIdx.y;
    int js = blockIdx.x;
    int j0 = js * 32 + (js * 32 >= kb ? NBLK : 0);   // skip pivot tile
    double* Mb = M + (long)b * KD * KD;
    int t = threadIdx.x;
    for (int i = t; i < NBLK * NBLK; i += 256)
        Ps[i >> 6][i & 63] = Mb[(long)(kb + (i >> 6)) * KD + kb + (i & 63)];
    for (int i = t; i < NBLK * 32; i += 256) {
        int r = i >> 5, c = i & 31;
        Ts[r][c] = Mb[(long)(kb + r) * KD + j0 + c];
    }
    __syncthreads();
    int tr4 = (t >> 4) * 4;        // 16 row-groups of 4
    int tc2 = (t & 15) * 2;        // 16 col-pairs
    double acc[4][2] = {};
    for (int kk = 0; kk < NBLK; kk++) {
        double bv0 = Ts[kk][tc2], bv1 = Ts[kk][tc2 + 1];
#pragma unroll
        for (int i = 0; i < 4; i++) {
            double a = Ps[tr4 + i][kk];
            acc[i][0] += a * bv0;
            acc[i][1] += a * bv1;
        }
    }
#pragma unroll
    for (int i = 0; i < 4; i++) {
        Mb[(long)(kb + tr4 + i) * KD + j0 + tc2]     = acc[i][0];
        Mb[(long)(kb + tr4 + i) * KD + j0 + tc2 + 1] = acc[i][1];
    }
}

// ---------- GJ step (fp64): trailing elimination + pivot-column update ----------
// cols split {p*32+tx*2}: conflict-free LDS reads, coalesced double2 global R/W.
__global__ __launch_bounds__(256, 2)
void k_elim_d(double* __restrict__ M, const double* __restrict__ Ft, int kb) {
    __shared__ double Fs[16][NBLK + 2];    // Fs[kcol][row]
    __shared__ double Rs[16][132];         // Rs[krow][col]
    int b = blockIdx.z;
    int it = blockIdx.y;
    int kt = kb / NBLK;
    if (it == kt) return;
    int i0 = it * NBLK;
    int j0 = blockIdx.x * 128;
    double* Mb = M + (long)b * KD * KD;
    const double* Fb = Ft + ((long)b * KD + i0) * NBLK;
    const double* Rrow = Mb + (long)kb * KD;
    int t = threadIdx.x, ty = t >> 4, tx = t & 15;
    double acc[4][8] = {};
    for (int kc = 0; kc < NBLK; kc += 16) {
        __syncthreads();
        for (int i = t; i < 16 * NBLK; i += 256) {
            int r = i >> 4, c = i & 15;
            Fs[c][r] = Fb[(long)r * NBLK + kc + c];
        }
        for (int i = t; i < 16 * 128; i += 256) {
            int r = i >> 7, c = i & 127;
            Rs[r][c] = Rrow[(long)(kc + r) * KD + j0 + c];
        }
        __syncthreads();
#pragma unroll
        for (int kk = 0; kk < 16; kk++) {
            double a[4], bv[8];
#pragma unroll
            for (int i = 0; i < 4; i++) a[i] = Fs[kk][ty * 4 + i];
#pragma unroll
            for (int p = 0; p < 4; p++) {
                bv[p * 2 + 0] = Rs[kk][p * 32 + tx * 2 + 0];
                bv[p * 2 + 1] = Rs[kk][p * 32 + tx * 2 + 1];
            }
#pragma unroll
            for (int i = 0; i < 4; i++)
#pragma unroll
                for (int j = 0; j < 8; j++)
                    acc[i][j] += a[i] * bv[j];
        }
    }
#pragma unroll
    for (int i = 0; i < 4; i++) {
        int r = i0 + ty * 4 + i;
#pragma unroll
        for (int p = 0; p < 4; p++) {
            int c = j0 + p * 32 + tx * 2;
            bool piv = (c >= kb && c < kb + NBLK);
            double b0 = piv ? 0.0 : Mb[(long)r * KD + c];
            double b1 = piv ? 0.0 : Mb[(long)r * KD + c + 1];
            Mb[(long)r * KD + c]     = b0 - acc[i][p * 2 + 0];
            Mb[(long)r * KD + c + 1] = b1 - acc[i][p * 2 + 1];
        }
    }
}

// ---------- compact a0/fr (shifted, zero pad); zero vd; seed sd = f0 ----------
__global__ void k_compact(const float* __restrict__ A, const float* __restrict__ fi,
                          double* __restrict__ a0c, double* __restrict__ frc,
                          double* __restrict__ vd, double* __restrict__ sd) {
    int idx = blockIdx.x * 256 + threadIdx.x;   // BB*KD
    int b = idx >> 10, i = idx & (KD - 1);
    a0c[idx] = (i < KD - 1) ? (double)A[((long)b << 20) + ((long)(i + 1) << 10)] : 0.0;
    frc[idx] = (i < KD - 1) ? (double)fi[(b << 10) + i + 1] : 0.0;
    vd[idx] = 0.0;
    if (i == 0) sd[b] = (double)fi[idx];        // s starts at f0; k_w accumulates fr.w
}

// ---------- w = Tinv @ a0 (wave per row); fold s += fr[r]*w[r] via atomics ----------
// s = f0 + v.a0 = f0 + fr^T Tinv a0 = f0 + fr.w  (same bilinear form)
__global__ void k_w(const double* __restrict__ Td, const double* __restrict__ a0c,
                    const double* __restrict__ frc, double* __restrict__ wd, double* __restrict__ sd) {
    int w = (blockIdx.x * 256 + threadIdx.x) >> 6;   // BB*KD waves
    int lane = threadIdx.x & 63;
    int b = w >> 10, r = w & (KD - 1);
    const double* Tb = Td + ((long)b << 20);
    const double* ab = a0c + (b << 10);
    double s = 0.0;
    for (int j = lane; j < KD; j += 64) s += Tb[((long)r << 10) + j] * ab[j];
    for (int off = 32; off; off >>= 1) s += __shfl_down(s, off);
    if (lane == 0) {
        wd[(b << 10) + r] = s;
        atomicAdd(&sd[b], frc[(b << 10) + r] * s);   // frc[1023]=0 pad keeps this exact
    }
}

// ---------- v = fr^T @ Tinv  (split-K over i-chunks, fp64 atomics) ----------
__global__ void k_v(const double* __restrict__ Td, const double* __restrict__ frc, double* __restrict__ vd) {
    int b = blockIdx.z;
    int j = blockIdx.x * 256 + threadIdx.x;
    int i0 = blockIdx.y * 128;
    const double* Tb = Td + ((long)b << 20);
    const double* fb = frc + (b << 10);
    double s = 0.0;
    for (int i = i0; i < i0 + 128; i++) s += fb[i] * Tb[((long)i << 10) + j];
    atomicAdd(&vd[(b << 10) + j], s);
}

// ---------- dgv[k] = Linv[k][k], d0[k] = f_k * Linv[k][0] ----------
__global__ void k_dgv(const double* __restrict__ Td, const double* __restrict__ wd,
                      const double* __restrict__ vd, const double* __restrict__ sd,
                      const float* __restrict__ fi, double* __restrict__ dgvd, float* __restrict__ d0) {
    int idx = blockIdx.x * 256 + threadIdx.x;  // BB*KD
    int b = idx >> 10, k = idx & (KD - 1);
    double rs = 1.0 / sd[b];
    if (k == 0) {
        dgvd[idx] = rs;
        d0[idx] = (float)((double)fi[idx] * rs);
    } else {
        int i = k - 1;
        dgvd[idx] = Td[((long)b << 20) + ((long)i << 10) + i] - wd[(b << 10) + i] * vd[(b << 10) + i] * rs;
        d0[idx] = (float)((double)fi[idx] * wd[(b << 10) + i] * rs);
    }
}

// ---------- a_ik in place over A via bordered-inverse algebra ----------
__global__ __launch_bounds__(256)
void k_aik2(float* __restrict__ A, const double* __restrict__ Td,
            const double* __restrict__ wd, const double* __restrict__ vd,
            const double* __restrict__ dgvd, const double* __restrict__ sd) {
    __shared__ double Tt[64][65];
    __shared__ double wls[64], vls[64], dgl[64];
    int b = blockIdx.z;
    int k0 = blockIdx.x * 64, j0 = blockIdx.y * 64;
    const double* Tb = Td + ((long)b << 20);
    int t = threadIdx.x;
    for (int i = t; i < 64 * 64; i += 256) {
        int kl = i >> 6, jl = i & 63;
        int kk = k0 + kl - 1, jj = j0 + jl - 1;
        Tt[kl][jl] = (kk >= 0 && jj >= 0) ? Tb[((long)kk << 10) + jj] : 0.0;
    }
    if (t < 64) {
        wls[t] = (k0 + t >= 1) ? wd[(b << 10) + k0 + t - 1] : 0.0;
        vls[t] = (j0 + t >= 1) ? vd[(b << 10) + j0 + t - 1] : 0.0;
        dgl[t] = dgvd[(b << 10) + k0 + t];
    }
    __syncthreads();
    double rs = 1.0 / sd[b];
    int kl = t & 63;
    int k = k0 + kl;
    double dv = dgl[kl], wk = wls[kl];
    for (int pass = 0; pass < 16; pass++) {
        int jl = (t >> 6) + pass * 4;
        int j = j0 + jl;
        long idx = ((long)(b << 10) + j) * KD + k;
        double a = (double)A[idx];
        double out;
        if (k == 0)      out = (j == 0) ? 0.0 : a * vls[jl] * rs;
        else if (j == 0) out = a * dv;
        else             out = a * (dv - Tt[kl][jl] + wk * vls[jl] * rs);
        A[idx] = (float)out;
    }
}

// ---------- a_ki output (transpose + d0 first column) ----------
__global__ void k_aki(const float* __restrict__ A, const float* __restrict__ d0, float* __restrict__ out) {
    __shared__ float T[64][65];
    int b = blockIdx.z;
    int i0 = blockIdx.y * 64;
    int k0 = blockIdx.x * 64;
    const float* Ab = A + (long)b * KD * KD;
    int t = threadIdx.x;
    for (int i = t; i < 64 * 64; i += 256) {
        int r = i / 64, c = i % 64;
        T[r][c] = Ab[(long)(i0 + r) * KD + k0 + c];
    }
    __syncthreads();
    float* ob = out + (long)b * KD * (KD + 1);
    int iloc = t % 64, kl0 = (t / 64) * 16;
    for (int kk = kl0; kk < kl0 + 16; kk++) {
        int kg = k0 + kk;
        ob[(long)kg * (KD + 1) + 1 + i0 + iloc] = T[iloc][kk];
    }
    if (blockIdx.y == 0 && t < 64) {
        int kg = k0 + t;
        ob[(long)kg * (KD + 1)] = d0[b * KD + kg];
    }
}

// ---------- si = a_ik^T @ e_i + d0 (x) exparam ----------
__global__ __launch_bounds__(256, 2)
void k_si16(const float* __restrict__ Aik, const float* __restrict__ E,
            const float* __restrict__ d0, const float* __restrict__ expar,
            float* __restrict__ Si) {
    __shared__ float As[16][132];
    __shared__ float Bs[16][132];
    int b = blockIdx.z;
    int m0 = blockIdx.x * 128;   // k
    int n0 = blockIdx.y * 128;   // s
    const float* Ab = Aik + (long)b * KD * KD;
    const float* Eb = E + (long)b * KD * SS;
    int t = threadIdx.x, ty = t / 16, tx = t % 16;
    int lb_r = t / 16, lb_c = (t % 16) * 4;
    float acc[8][8] = {};
    for (int j0 = 0; j0 < KD; j0 += 16) {
        float4 a0 = *(const float4*)&Ab[(long)(j0 + lb_r) * KD + m0 + lb_c];
        float4 a1 = *(const float4*)&Ab[(long)(j0 + lb_r) * KD + m0 + 64 + lb_c];
        float4 b0 = *(const float4*)&Eb[(long)(j0 + lb_r) * SS + n0 + lb_c];
        float4 b1 = *(const float4*)&Eb[(long)(j0 + lb_r) * SS + n0 + 64 + lb_c];
        __syncthreads();
        *(float4*)&As[lb_r][lb_c] = a0;
        *(float4*)&As[lb_r][64 + lb_c] = a1;
        *(float4*)&Bs[lb_r][lb_c] = b0;
        *(float4*)&Bs[lb_r][64 + lb_c] = b1;
        __syncthreads();
        mac16(acc, As, Bs, ty, tx);
    }
#pragma unroll
    for (int i = 0; i < 8; i++) {
        int row = m0 + (i < 4 ? ty * 4 + i : 64 + ty * 4 + i - 4);
        float dr = d0[b * KD + row];
        float4 o0, o1;
        float* p0 = &o0.x; float* p1 = &o1.x;
#pragma unroll
        for (int j = 0; j < 4; j++) {
            p0[j] = acc[i][j] + dr * expar[n0 + tx * 4 + j];
            p1[j] = acc[i][j + 4] + dr * expar[n0 + 64 + tx * 4 + j];
        }
        *(float4*)&Si[((long)b * KD + row) * SS + n0 + tx * 4] = o0;
        *(float4*)&Si[((long)b * KD + row) * SS + n0 + 64 + tx * 4] = o1;
    }
}

// ---------- ci = a_ik @ e_i ----------
__global__ __launch_bounds__(256, 2)
void k_ci16(const float* __restrict__ Aik, const float* __restrict__ E, float* __restrict__ Ci) {
    __shared__ float As[16][132];
    __shared__ float Bs[16][132];
    int b = blockIdx.z;
    int m0 = blockIdx.x * 128;
    int n0 = blockIdx.y * 128;
    const float* Ab = Aik + (long)b * KD * KD;
    const float* Eb = E + (long)b * KD * SS;
    int t = threadIdx.x, ty = t / 16, tx = t % 16;
    int la_r = t / 4, la_c = (t % 4) * 4;
    int lb_r = t / 16, lb_c = (t % 16) * 4;
    float acc[8][8] = {};
    for (int k0 = 0; k0 < KD; k0 += 16) {
        float4 a0 = *(const float4*)&Ab[(long)(m0 + la_r) * KD + k0 + la_c];
        float4 a1 = *(const float4*)&Ab[(long)(m0 + 64 + la_r) * KD + k0 + la_c];
        float4 b0 = *(const float4*)&Eb[(long)(k0 + lb_r) * SS + n0 + lb_c];
        float4 b1 = *(const float4*)&Eb[(long)(k0 + lb_r) * SS + n0 + 64 + lb_c];
        __syncthreads();
        storeA_t(As, a0, a1, la_r, la_c);
        *(float4*)&Bs[lb_r][lb_c] = b0;
        *(float4*)&Bs[lb_r][64 + lb_c] = b1;
        __syncthreads();
        mac16(acc, As, Bs, ty, tx);
    }
#pragma unroll
    for (int i = 0; i < 8; i++) {
        int row = m0 + (i < 4 ? ty * 4 + i : 64 + ty * 4 + i - 4);
        *(float4*)&Ci[((long)b * KD + row) * SS + n0 + tx * 4] = *(float4*)&acc[i][0];
        *(float4*)&Ci[((long)b * KD + row) * SS + n0 + 64 + tx * 4] = *(float4*)&acc[i][4];
    }
}

// ---------- r_i = tanh([e,si,ci] @ Wr + br) ----------
__global__ __launch_bounds__(256, 2)
void k_ri16(const float* __restrict__ E, const float* __restrict__ Si, const float* __restrict__ Ci,
            const float* __restrict__ Wr, const float* __restrict__ br, float* __restrict__ out) {
    __shared__ float As[16][132];
    __shared__ float Bs[16][132];
    int m0 = blockIdx.x * 128, n0 = blockIdx.y * 128;
    int t = threadIdx.x, ty = t / 16, tx = t % 16;
    int la_r = t / 4, la_c = (t % 4) * 4;
    int lb_r = t / 16, lb_c = (t % 16) * 4;
    float acc[8][8] = {};
    const float* srcs[3] = {E, Si, Ci};
    for (int seg = 0; seg < 3; seg++) {
        const float* Sp = srcs[seg];
        for (int k0 = 0; k0 < SS; k0 += 16) {
            float4 a0 = *(const float4*)&Sp[(long)(m0 + la_r) * SS + k0 + la_c];
            float4 a1 = *(const float4*)&Sp[(long)(m0 + 64 + la_r) * SS + k0 + la_c];
            float4 b0 = *(const float4*)&Wr[(long)(seg * SS + k0 + lb_r) * SS + n0 + lb_c];
            float4 b1 = *(const float4*)&Wr[(long)(seg * SS + k0 + lb_r) * SS + n0 + 64 + lb_c];
            __syncthreads();
            storeA_t(As, a0, a1, la_r, la_c);
            *(float4*)&Bs[lb_r][lb_c] = b0;
            *(float4*)&Bs[lb_r][64 + lb_c] = b1;
            __syncthreads();
            mac16(acc, As, Bs, ty, tx);
        }
    }
#pragma unroll
    for (int i = 0; i < 8; i++) {
        int row = m0 + (i < 4 ? ty * 4 + i : 64 + ty * 4 + i - 4);
        float4 o0, o1;
        float* p0 = &o0.x; float* p1 = &o1.x;
#pragma unroll
        for (int j = 0; j < 4; j++) {
            p0[j] = tanhf(acc[i][j] + br[n0 + tx * 4 + j]);
            p1[j] = tanhf(acc[i][j + 4] + br[n0 + 64 + tx * 4 + j]);
        }
        *(float4*)&out[(long)row * SS + n0 + tx * 4] = o0;
        *(float4*)&out[(long)row * SS + n0 + 64 + tx * 4] = o1;
    }
}

extern "C" void kernel_launch(void* const* d_in, const int* in_sizes, int n_in,
                              void* d_out, int out_size, void* d_ws, size_t ws_size,
                              hipStream_t stream) {
    const float* x     = (const float*)d_in[0];
    const float* Wp_w  = (const float*)d_in[1];
    const float* Wp_b  = (const float*)d_in[2];
    const float* Wc_w  = (const float*)d_in[3];
    const float* Wc_b  = (const float*)d_in[4];
    const float* fi_w  = (const float*)d_in[5];
    const float* Wa_w  = (const float*)d_in[6];
    const float* expar = (const float*)d_in[7];
    const float* Wr_w  = (const float*)d_in[8];
    const float* Wr_b  = (const float*)d_in[9];

    float* ws = (float*)d_ws;
    // Region R (offset 23,068,672, span 33,554,432 f32 = 128 MB) is time-multiplexed:
    // early {di/tt, uj, uk}; mid: Td (fp64 padded T matrix -> Tinv); late: {si, ci}.
    float*  A    = ws;                               // 16,777,216 f32 (S -> A -> a_ik)
    float*  ei   = ws + 16777216;                    //  6,291,456 f32
    float*  R    = ws + 23068672;
    float*  di   = R;
    float*  uj   = R + 6291456;
    float*  uk   = R + 12582912;
    float*  tt   = di;
    double* Td   = (double*)R;                       // 16,777,216 doubles = 128 MB
    float*  sbuf = R;                                // after Td dead
    float*  cbuf = R + 6291456;
    double* Ftd  = (double*)(ws + 56623104);         // 1,048,576 doubles = 8 MB
    float*  g    = ws + 58720256;                    // 16,384
    float*  mcol = ws + 58736640;                    // 16,384
    float*  fi   = ws + 58753024;                    // 16,384
    float*  d0   = ws + 58769408;                    // 16,384
    double* csd  = (double*)(ws + 58785792);         // 16,384 doubles
    double* wd   = (double*)(ws + 58818560);         // 16,384 doubles
    double* vd   = (double*)(ws + 58851328);         // 16,384 doubles
    double* dgvd = (double*)(ws + 58884096);         // 16,384 doubles
    double* a0c  = (double*)(ws + 58916864);         // 16,384 doubles
    double* frc  = (double*)(ws + 58949632);         // 16,384 doubles
    double* sd   = (double*)(ws + 58982400);         // 16 doubles; end ~236 MB

    float* r_out   = (float*)d_out;
    float* aki_out = r_out + (long)BB * KD * SS;
    // aki output region (64 MB) is dead until k_aki: borrow 1 MB as colmax scratch.
    float* pmax    = aki_out;                        // 16 * 16384 f32

    k_prep<<<BB * KD * SS / 256, 256, 0, stream>>>(x, di, ei);
    k_gemm_pc<<<dim3(128, 6), 256, 0, stream>>>(di, Wp_w, Wp_b, Wc_w, Wc_b, uj, uk);
    k_firaw<<<BB * KD / 4, 256, 0, stream>>>(di, fi_w, g);
    k_gemm16<false, false><<<dim3(128, 3), 256, 0, stream>>>(uj, Wa_w, nullptr, tt, BB * KD, SS, SS);
    k_fjk16<<<dim3(8, 8, BB), 256, 0, stream>>>(tt, uk, A);
    k_colmax1<<<dim3(BB * KD / 256, 16), 256, 0, stream>>>(A, pmax);
    k_colmax2<<<BB * KD / 256, 256, 0, stream>>>(pmax, g, mcol, fi, csd);
    k_expA_sum<<<dim3(16, 16, BB), 256, 0, stream>>>(A, mcol, csd);
    k_buildT<<<BB * KD * KD / 256, 256, 0, stream>>>(A, csd, Td);

    for (int s = 0; s < KD / NBLK; s++) {
        int kb = s * NBLK;
        k_diagsave_d<<<BB * KD * NBLK / 256 + BB, 256, 0, stream>>>(Td, Ftd, kb);
        k_rowcol_d<<<dim3((KD - NBLK) / 32, BB), 256, 0, stream>>>(Td, kb);
        k_elim_d<<<dim3(8, 16, BB), 256, 0, stream>>>(Td, Ftd, kb);
    }

    k_compact<<<BB * KD / 256, 256, 0, stream>>>(A, fi, a0c, frc, vd, sd);
    k_w<<<BB * KD / 4, 256, 0, stream>>>(Td, a0c, frc, wd, sd);
    k_v<<<dim3(4, 8, BB), 256, 0, stream>>>(Td, frc, vd);
    k_dgv<<<BB * KD / 256, 256, 0, stream>>>(Td, wd, vd, sd, fi, dgvd, d0);
    k_aik2<<<dim3(16, 16, BB), 256, 0, stream>>>(A, Td, wd, vd, dgvd, sd);
    k_aki<<<dim3(16, 16, BB), 256, 0, stream>>>(A, d0, aki_out);
    k_si16<<<dim3(8, 3, BB), 256, 0, stream>>>(A, ei, d0, expar, sbuf);
    k_ci16<<<dim3(8, 3, BB), 256, 0, stream>>>(A, ei, cbuf);
    k_ri16<<<dim3(128, 3), 256, 0, stream>>>(ei, sbuf, cbuf, Wr_w, Wr_b, r_out);
}

// Round 8
// 4479.314 us; speedup vs baseline: 1.0072x; 1.0072x over previous
//
#include <hip/hip_runtime.h>

#define BB 16
#define KD 1024
#define DD 768
#define SS 384
#define HH 192
#define NBLK 64

// ================= 128x128xBK16 fp32 GEMM micro-core (mac16) =================
// 256 threads, 8x8 acc per thread, rows {ty*4, 64+ty*4}, cols {tx*4, 64+tx*4}.
__device__ __forceinline__ void mac16(float (&acc)[8][8], const float (*As)[132], const float (*Bs)[132],
                                      int ty, int tx) {
#pragma unroll
    for (int kk = 0; kk < 16; kk++) {
        float a[8], b[8];
        *(float4*)&a[0] = *(const float4*)&As[kk][ty * 4];
        *(float4*)&a[4] = *(const float4*)&As[kk][64 + ty * 4];
        *(float4*)&b[0] = *(const float4*)&Bs[kk][tx * 4];
        *(float4*)&b[4] = *(const float4*)&Bs[kk][64 + tx * 4];
#pragma unroll
        for (int i = 0; i < 8; i++)
#pragma unroll
            for (int j = 0; j < 8; j++)
                acc[i][j] += a[i] * b[j];
    }
}

// ================= 128x64xBK16 fp32 micro-core (mac16n) =================
// 256 threads, 8x4 acc per thread. 768-block grids -> 3 blocks/CU, no tail.
__device__ __forceinline__ void mac16n(float (&acc)[8][4], const float (*As)[132], const float (*Bs)[68],
                                       int ty, int tx) {
#pragma unroll
    for (int kk = 0; kk < 16; kk++) {
        float a[8], b[4];
        *(float4*)&a[0] = *(const float4*)&As[kk][ty * 4];
        *(float4*)&a[4] = *(const float4*)&As[kk][64 + ty * 4];
        *(float4*)&b[0] = *(const float4*)&Bs[kk][tx * 4];
#pragma unroll
        for (int i = 0; i < 8; i++)
#pragma unroll
            for (int j = 0; j < 4; j++)
                acc[i][j] += a[i] * b[j];
    }
}

// transpose-store an A-style tile (row-major MxK source chunk) into As[k][m]
__device__ __forceinline__ void storeA_t(float (*As)[132], const float4& v0, const float4& v1,
                                         int la_r, int la_c) {
    As[la_c + 0][la_r] = v0.x; As[la_c + 1][la_r] = v0.y;
    As[la_c + 2][la_r] = v0.z; As[la_c + 3][la_r] = v0.w;
    As[la_c + 0][64 + la_r] = v1.x; As[la_c + 1][64 + la_r] = v1.y;
    As[la_c + 2][64 + la_r] = v1.z; As[la_c + 3][64 + la_r] = v1.w;
}

// ---------- split x into e_i / d_i ----------
__global__ void k_prep(const float* __restrict__ x, float* __restrict__ di, float* __restrict__ ei) {
    int idx = blockIdx.x * 256 + threadIdx.x;       // over BB*KD*SS
    int s = idx % SS;
    long bk = idx / SS;
    const float* xr = x + bk * DD;
    ei[idx] = xr[s < HH ? s : s + HH];
    di[idx] = xr[s < HH ? s + HH : s + 2 * HH];
}

// ---------- generic fp32 NN GEMM, 128x64 tile: C = act(A[M,Kd] @ B[Kd,N] + bias) ----------
template<bool BIAS, bool TANH>
__global__ __launch_bounds__(256, 2)
void k_gemm64(const float* __restrict__ A, const float* __restrict__ Bw,
              const float* __restrict__ bias, float* __restrict__ C,
              int M, int N, int Kd) {
    __shared__ float As[16][132];
    __shared__ float Bs[16][68];
    int m0 = blockIdx.x * 128, n0 = blockIdx.y * 64;
    int t = threadIdx.x;
    int ty = t / 16, tx = t % 16;
    int la_r = t / 4, la_c = (t % 4) * 4;
    int lb_r = t / 16, lb_c = (t % 16) * 4;
    float acc[8][4] = {};
    for (int k0 = 0; k0 < Kd; k0 += 16) {
        float4 a0 = *(const float4*)&A[(long)(m0 + la_r) * Kd + k0 + la_c];
        float4 a1 = *(const float4*)&A[(long)(m0 + 64 + la_r) * Kd + k0 + la_c];
        float4 b0 = *(const float4*)&Bw[(long)(k0 + lb_r) * N + n0 + lb_c];
        __syncthreads();
        storeA_t(As, a0, a1, la_r, la_c);
        *(float4*)&Bs[lb_r][lb_c] = b0;
        __syncthreads();
        mac16n(acc, As, Bs, ty, tx);
    }
#pragma unroll
    for (int i = 0; i < 8; i++) {
        int row = m0 + (i < 4 ? ty * 4 + i : 64 + ty * 4 + i - 4);
        float4 o0;
        float* p0 = &o0.x;
#pragma unroll
        for (int j = 0; j < 4; j++) {
            float v = acc[i][j];
            if (BIAS) v += bias[n0 + tx * 4 + j];
            if (TANH) v = tanhf(v);
            p0[j] = v;
        }
        *(float4*)&C[(long)row * N + n0 + tx * 4] = o0;
    }
}

// ---------- merged parent/child transforms: uj = tanh(di@Wp+bp), uk = tanh(di@Wc+bc) ----------
// grid (128, 6): y<3 -> {Wp,bp,uj}, else {Wc,bc,uk}. Same A tiles, one launch.
__global__ __launch_bounds__(256, 2)
void k_gemm_pc(const float* __restrict__ A, const float* __restrict__ Wp,
               const float* __restrict__ bp, const float* __restrict__ Wc,
               const float* __restrict__ bc, float* __restrict__ Uj, float* __restrict__ Uk) {
    __shared__ float As[16][132];
    __shared__ float Bs[16][132];
    bool first = blockIdx.y < 3;
    const float* Bw = first ? Wp : Wc;
    const float* bias = first ? bp : bc;
    float* C = first ? Uj : Uk;
    int m0 = blockIdx.x * 128, n0 = (blockIdx.y % 3) * 128;
    int t = threadIdx.x;
    int ty = t / 16, tx = t % 16;
    int la_r = t / 4, la_c = (t % 4) * 4;
    int lb_r = t / 16, lb_c = (t % 16) * 4;
    float acc[8][8] = {};
    for (int k0 = 0; k0 < SS; k0 += 16) {
        float4 a0 = *(const float4*)&A[(long)(m0 + la_r) * SS + k0 + la_c];
        float4 a1 = *(const float4*)&A[(long)(m0 + 64 + la_r) * SS + k0 + la_c];
        float4 b0 = *(const float4*)&Bw[(long)(k0 + lb_r) * SS + n0 + lb_c];
        float4 b1 = *(const float4*)&Bw[(long)(k0 + lb_r) * SS + n0 + 64 + lb_c];
        __syncthreads();
        storeA_t(As, a0, a1, la_r, la_c);
        *(float4*)&Bs[lb_r][lb_c] = b0;
        *(float4*)&Bs[lb_r][64 + lb_c] = b1;
        __syncthreads();
        mac16(acc, As, Bs, ty, tx);
    }
#pragma unroll
    for (int i = 0; i < 8; i++) {
        int row = m0 + (i < 4 ? ty * 4 + i : 64 + ty * 4 + i - 4);
        float4 o0, o1;
        float* p0 = &o0.x; float* p1 = &o1.x;
#pragma unroll
        for (int j = 0; j < 4; j++) {
            p0[j] = tanhf(acc[i][j] + bias[n0 + tx * 4 + j]);
            p1[j] = tanhf(acc[i][j + 4] + bias[n0 + 64 + tx * 4 + j]);
        }
        *(float4*)&C[(long)row * SS + n0 + tx * 4] = o0;
        *(float4*)&C[(long)row * SS + n0 + 64 + tx * 4] = o1;
    }
}

// ---------- batched NT GEMM: S[b,j,k] = sum_s T[b,j,s]*Uk[b,k,s]  (raw scores) ----------
__global__ __launch_bounds__(256, 2)
void k_fjk16(const float* __restrict__ T, const float* __restrict__ Uk, float* __restrict__ Sout) {
    __shared__ float As[16][132];
    __shared__ float Bs[16][132];
    int b = blockIdx.z;
    const float* Ab = T + (long)b * KD * SS;
    const float* Bb = Uk + (long)b * KD * SS;
    int m0 = blockIdx.x * 128, n0 = blockIdx.y * 128;
    int t = threadIdx.x;
    int ty = t / 16, tx = t % 16;
    int la_r = t / 4, la_c = (t % 4) * 4;
    float acc[8][8] = {};
    for (int k0 = 0; k0 < SS; k0 += 16) {
        float4 a0 = *(const float4*)&Ab[(long)(m0 + la_r) * SS + k0 + la_c];
        float4 a1 = *(const float4*)&Ab[(long)(m0 + 64 + la_r) * SS + k0 + la_c];
        float4 b0 = *(const float4*)&Bb[(long)(n0 + la_r) * SS + k0 + la_c];
        float4 b1 = *(const float4*)&Bb[(long)(n0 + 64 + la_r) * SS + k0 + la_c];
        __syncthreads();
        storeA_t(As, a0, a1, la_r, la_c);
        storeA_t(Bs, b0, b1, la_r, la_c);
        __syncthreads();
        mac16(acc, As, Bs, ty, tx);
    }
#pragma unroll
    for (int i = 0; i < 8; i++) {
        int row = m0 + (i < 4 ? ty * 4 + i : 64 + ty * 4 + i - 4);
        *(float4*)&Sout[((long)b * KD + row) * KD + n0 + tx * 4] = *(float4*)&acc[i][0];
        *(float4*)&Sout[((long)b * KD + row) * KD + n0 + 64 + tx * 4] = *(float4*)&acc[i][4];
    }
}

// ---------- raw root logit g = d_i . fi_w ----------
__global__ void k_firaw(const float* __restrict__ di, const float* __restrict__ fiw, float* __restrict__ g) {
    int w = (blockIdx.x * 256 + threadIdx.x) / 64;
    int lane = threadIdx.x % 64;
    if (w >= BB * KD) return;
    const float* dr = di + (long)w * SS;
    float s = 0.f;
    for (int i = lane; i < SS; i += 64) s += dr[i] * fiw[i];
    for (int off = 32; off; off >>= 1) s += __shfl_down(s, off);
    if (lane == 0) g[w] = s;
}

// ---------- per-column max, stage 1: partial over 64-row j-chunks ----------
__global__ void k_colmax1(const float* __restrict__ S, float* __restrict__ pmax) {
    int idx = blockIdx.x * 256 + threadIdx.x;   // BB*KD
    int jt = blockIdx.y;                        // 16 j-chunks of 64
    int b = idx >> 10, k = idx & (KD - 1);
    const float* Sb = S + (long)b * KD * KD;
    float m = -3.4e38f;
    for (int j = jt * 64; j < jt * 64 + 64; j++) {
        float v = Sb[(long)j * KD + k];
        m = fmaxf(m, (j == k) ? -3.4e38f : v);
    }
    pmax[((long)jt << 14) + idx] = m;
}

// ---------- per-column max, stage 2: reduce partials + fold g; fi = exp(g-m); zero csd ----------
__global__ void k_colmax2(const float* __restrict__ pmax, const float* __restrict__ g,
                          float* __restrict__ mcol, float* __restrict__ fi, double* __restrict__ csd) {
    int idx = blockIdx.x * 256 + threadIdx.x;   // BB*KD
    float gv = g[idx];
    float m = gv;
    for (int jt = 0; jt < 16; jt++) m = fmaxf(m, pmax[((long)jt << 14) + idx]);
    mcol[idx] = m;
    fi[idx] = expf(gv - m);
    csd[idx] = 0.0;                             // prepare for fused col-sum atomics
}

// ---------- A = exp(S - m_col) (diag zeroed, in place) + fused fp64 column sums ----------
// 64x64 tile per block; per-column partial reduced in LDS, one atomicAdd per col per j-tile.
__global__ __launch_bounds__(256)
void k_expA_sum(float* __restrict__ S, const float* __restrict__ mcol, double* __restrict__ csd) {
    __shared__ double red[4][64];
    int b = blockIdx.z, jt = blockIdx.y, kt = blockIdx.x;
    int t = threadIdx.x;
    int tc = t & 63, tg = t >> 6;               // col in tile, row-group (4x16 rows)
    int kg = kt * 64 + tc;
    float mc = mcol[(b << 10) + kg];
    float* Sb = S + ((long)b << 20);
    double s = 0.0;
    for (int rr = 0; rr < 16; rr++) {
        int j = jt * 64 + tg * 16 + rr;
        long a = ((long)j << 10) + kg;
        float v = (j == kg) ? 0.f : expf(Sb[a] - mc);
        Sb[a] = v;
        s += (double)v;
    }
    red[tg][tc] = s;
    __syncthreads();
    if (tg == 0) {
        double tot = red[0][tc] + red[1][tc] + red[2][tc] + red[3][tc];
        atomicAdd(&csd[(b << 10) + kg], tot);
    }
}

// ---------- build padded T~ (fp64): T[i][j] = L[1+i][1+j] for i,j<1023; identity pad at 1023 ----------
__global__ void k_buildT(const float* __restrict__ A, const double* __restrict__ csd, double* __restrict__ Td) {
    long idx = (long)blockIdx.x * 256 + threadIdx.x;  // BB*KD*KD
    int j = idx & (KD - 1);
    int i = (int)(idx >> 10) & (KD - 1);
    int b = (int)(idx >> 20);
    double v;
    if (i == KD - 1 || j == KD - 1) v = (i == j) ? 1.0 : 0.0;
    else if (i == j) v = csd[(b << 10) + j + 1];
    else v = -(double)A[((long)b << 20) + ((long)(i + 1) << 10) + (j + 1)];
    Td[idx] = v;
}

// ---------- GJ step (fp64): fused {savecol || diag} ----------
// savecol blocks copy the pivot-column block M[:, kb:kb+64] to Ft; diag blocks
// invert the 64x64 diagonal block in LDS. Independent: diag writes only rows
// kb..kb+63 of the pivot column, and those Ft rows (it==kt) are skipped by
// k_elim_d, so concurrent/torn reads of that sub-block are never consumed.
__global__ __launch_bounds__(256)
void k_diagsave_d(double* __restrict__ M, double* __restrict__ Ft, int kb) {
    __shared__ double P[NBLK][NBLK + 1];
    __shared__ double rowbuf[NBLK];
    const int nsave = BB * KD * NBLK / 256;   // 4096 copy blocks
    if ((int)blockIdx.x < nsave) {
        int idx = blockIdx.x * 256 + threadIdx.x;     // BB*KD*NBLK
        int c = idx % NBLK;
        int rk = idx / NBLK;
        int r = rk % KD, b = rk / KD;
        Ft[idx] = M[((long)b * KD + r) * KD + kb + c];
        return;
    }
    int b = blockIdx.x - nsave;
    double* Mb = M + (long)b * KD * KD;
    int t = threadIdx.x;
    for (int i = t; i < NBLK * NBLK; i += 256)
        P[i / NBLK][i % NBLK] = Mb[(long)(kb + i / NBLK) * KD + kb + i % NBLK];
    __syncthreads();
    int mi = t & 63;
    int c0 = (t >> 6) * 16;
    for (int kk = 0; kk < NBLK; kk++) {
        double p = 1.0 / P[kk][kk];
        double F = P[mi][kk];
        if (t < 64) rowbuf[t] = P[kk][t] * p;
        __syncthreads();
        if (mi == kk) {
            for (int c = c0; c < c0 + 16; c++)
                P[mi][c] = (c == kk) ? p : rowbuf[c];
        } else {
            for (int c = c0; c < c0 + 16; c++)
                P[mi][c] = (c == kk) ? (-F * p) : (P[mi][c] - F * rowbuf[c]);
        }
        __syncthreads();
    }
    for (int i = t; i < NBLK * NBLK; i += 256)
        Mb[(long)(kb + i / NBLK) * KD + kb + i % NBLK] = P[i / NBLK][i % NBLK];
}

// ---------- GJ step (fp64): pivot block-row update  M[k, strip] = Dinv @ M[k, strip] ----------
// 32-col strips, self-contained: each block reads the Dinv diagonal tile (read-only
// here) + its own 64x32 pivot-row strip into LDS, then overwrites the same strip.
// No cross-block hazard. grid (30, BB).
__global__ __launch_bounds__(256)
void k_rowcol_d(double* __restrict__ M, int kb) {
    __shared__ double Ps[NBLK][NBLK + 1];   // Dinv[r][k]
    __shared__ double Ts[NBLK][33];         // R[k][c] (32-col strip)
    int b = blockIdx.y;
    int js = blockIdx.x;
    int j0 = js * 32 + (js * 32 >= kb ? NBLK : 0);   // skip pivot tile
    double* Mb = M + (long)b * KD * KD;
    int t = threadIdx.x;
    for (int i = t; i < NBLK * NBLK; i += 256)
        Ps[i >> 6][i & 63] = Mb[(long)(kb + (i >> 6)) * KD + kb + (i & 63)];
    for (int i = t; i < NBLK * 32; i += 256) {
        int r = i >> 5, c = i & 31;
        Ts[r][c] = Mb[(long)(kb + r) * KD + j0 + c];
    }
    __syncthreads();
    int tr4 = (t >> 4) * 4;        // 16 row-groups of 4
    int tc2 = (t & 15) * 2;        // 16 col-pairs
    double acc[4][2] = {};
    for (int kk = 0; kk < NBLK; kk++) {
        double bv0 = Ts[kk][tc2], bv1 = Ts[kk][tc2 + 1];
#pragma unroll
        for (int i = 0; i < 4; i++) {
            double a = Ps[tr4 + i][kk];
            acc[i][0] += a * bv0;
            acc[i][1] += a * bv1;
        }
    }
#pragma unroll
    for (int i = 0; i < 4; i++) {
        Mb[(long)(kb + tr4 + i) * KD + j0 + tc2]     = acc[i][0];
        Mb[(long)(kb + tr4 + i) * KD + j0 + tc2 + 1] = acc[i][1];
    }
}

// ---------- GJ step (fp64): trailing elimination + pivot-column update ----------
// cols split {p*32+tx*2}: conflict-free LDS reads, coalesced double2 global R/W.
__global__ __launch_bounds__(256, 2)
void k_elim_d(double* __restrict__ M, const double* __restrict__ Ft, int kb) {
    __shared__ double Fs[16][NBLK + 2];    // Fs[kcol][row]
    __shared__ double Rs[16][132];         // Rs[krow][col]
    int b = blockIdx.z;
    int it = blockIdx.y;
    int kt = kb / NBLK;
    if (it == kt) return;
    int i0 = it * NBLK;
    int j0 = blockIdx.x * 128;
    double* Mb = M + (long)b * KD * KD;
    const double* Fb = Ft + ((long)b * KD + i0) * NBLK;
    const double* Rrow = Mb + (long)kb * KD;
    int t = threadIdx.x, ty = t >> 4, tx = t & 15;
    double acc[4][8] = {};
    for (int kc = 0; kc < NBLK; kc += 16) {
        __syncthreads();
        for (int i = t; i < 16 * NBLK; i += 256) {
            int r = i >> 4, c = i & 15;
            Fs[c][r] = Fb[(long)r * NBLK + kc + c];
        }
        for (int i = t; i < 16 * 128; i += 256) {
            int r = i >> 7, c = i & 127;
            Rs[r][c] = Rrow[(long)(kc + r) * KD + j0 + c];
        }
        __syncthreads();
#pragma unroll
        for (int kk = 0; kk < 16; kk++) {
            double a[4], bv[8];
#pragma unroll
            for (int i = 0; i < 4; i++) a[i] = Fs[kk][ty * 4 + i];
#pragma unroll
            for (int p = 0; p < 4; p++) {
                bv[p * 2 + 0] = Rs[kk][p * 32 + tx * 2 + 0];
                bv[p * 2 + 1] = Rs[kk][p * 32 + tx * 2 + 1];
            }
#pragma unroll
            for (int i = 0; i < 4; i++)
#pragma unroll
                for (int j = 0; j < 8; j++)
                    acc[i][j] += a[i] * bv[j];
        }
    }
#pragma unroll
    for (int i = 0; i < 4; i++) {
        int r = i0 + ty * 4 + i;
#pragma unroll
        for (int p = 0; p < 4; p++) {
            int c = j0 + p * 32 + tx * 2;
            bool piv = (c >= kb && c < kb + NBLK);
            double b0 = piv ? 0.0 : Mb[(long)r * KD + c];
            double b1 = piv ? 0.0 : Mb[(long)r * KD + c + 1];
            Mb[(long)r * KD + c]     = b0 - acc[i][p * 2 + 0];
            Mb[(long)r * KD + c + 1] = b1 - acc[i][p * 2 + 1];
        }
    }
}

// ---------- compact a0/fr (shifted, zero pad); zero vd; seed sd = f0 ----------
__global__ void k_compact(const float* __restrict__ A, const float* __restrict__ fi,
                          double* __restrict__ a0c, double* __restrict__ frc,
                          double* __restrict__ vd, double* __restrict__ sd) {
    int idx = blockIdx.x * 256 + threadIdx.x;   // BB*KD
    int b = idx >> 10, i = idx & (KD - 1);
    a0c[idx] = (i < KD - 1) ? (double)A[((long)b << 20) + ((long)(i + 1) << 10)] : 0.0;
    frc[idx] = (i < KD - 1) ? (double)fi[(b << 10) + i + 1] : 0.0;
    vd[idx] = 0.0;
    if (i == 0) sd[b] = (double)fi[idx];        // s starts at f0; k_w accumulates fr.w
}

// ---------- w = Tinv @ a0 (wave per row); fold s += fr[r]*w[r] via atomics ----------
// s = f0 + v.a0 = f0 + fr^T Tinv a0 = f0 + fr.w  (same bilinear form)
__global__ void k_w(const double* __restrict__ Td, const double* __restrict__ a0c,
                    const double* __restrict__ frc, double* __restrict__ wd, double* __restrict__ sd) {
    int w = (blockIdx.x * 256 + threadIdx.x) >> 6;   // BB*KD waves
    int lane = threadIdx.x & 63;
    int b = w >> 10, r = w & (KD - 1);
    const double* Tb = Td + ((long)b << 20);
    const double* ab = a0c + (b << 10);
    double s = 0.0;
    for (int j = lane; j < KD; j += 64) s += Tb[((long)r << 10) + j] * ab[j];
    for (int off = 32; off; off >>= 1) s += __shfl_down(s, off);
    if (lane == 0) {
        wd[(b << 10) + r] = s;
        atomicAdd(&sd[b], frc[(b << 10) + r] * s);   // frc[1023]=0 pad keeps this exact
    }
}

// ---------- v = fr^T @ Tinv  (split-K over i-chunks, fp64 atomics) ----------
__global__ void k_v(const double* __restrict__ Td, const double* __restrict__ frc, double* __restrict__ vd) {
    int b = blockIdx.z;
    int j = blockIdx.x * 256 + threadIdx.x;
    int i0 = blockIdx.y * 128;
    const double* Tb = Td + ((long)b << 20);
    const double* fb = frc + (b << 10);
    double s = 0.0;
    for (int i = i0; i < i0 + 128; i++) s += fb[i] * Tb[((long)i << 10) + j];
    atomicAdd(&vd[(b << 10) + j], s);
}

// ---------- dgv[k] = Linv[k][k], d0[k] = f_k * Linv[k][0] ----------
__global__ void k_dgv(const double* __restrict__ Td, const double* __restrict__ wd,
                      const double* __restrict__ vd, const double* __restrict__ sd,
                      const float* __restrict__ fi, double* __restrict__ dgvd, float* __restrict__ d0) {
    int idx = blockIdx.x * 256 + threadIdx.x;  // BB*KD
    int b = idx >> 10, k = idx & (KD - 1);
    double rs = 1.0 / sd[b];
    if (k == 0) {
        dgvd[idx] = rs;
        d0[idx] = (float)((double)fi[idx] * rs);
    } else {
        int i = k - 1;
        dgvd[idx] = Td[((long)b << 20) + ((long)i << 10) + i] - wd[(b << 10) + i] * vd[(b << 10) + i] * rs;
        d0[idx] = (float)((double)fi[idx] * wd[(b << 10) + i] * rs);
    }
}

// ---------- a_ik in place over A via bordered-inverse algebra ----------
__global__ __launch_bounds__(256)
void k_aik2(float* __restrict__ A, const double* __restrict__ Td,
            const double* __restrict__ wd, const double* __restrict__ vd,
            const double* __restrict__ dgvd, const double* __restrict__ sd) {
    __shared__ double Tt[64][65];
    __shared__ double wls[64], vls[64], dgl[64];
    int b = blockIdx.z;
    int k0 = blockIdx.x * 64, j0 = blockIdx.y * 64;
    const double* Tb = Td + ((long)b << 20);
    int t = threadIdx.x;
    for (int i = t; i < 64 * 64; i += 256) {
        int kl = i >> 6, jl = i & 63;
        int kk = k0 + kl - 1, jj = j0 + jl - 1;
        Tt[kl][jl] = (kk >= 0 && jj >= 0) ? Tb[((long)kk << 10) + jj] : 0.0;
    }
    if (t < 64) {
        wls[t] = (k0 + t >= 1) ? wd[(b << 10) + k0 + t - 1] : 0.0;
        vls[t] = (j0 + t >= 1) ? vd[(b << 10) + j0 + t - 1] : 0.0;
        dgl[t] = dgvd[(b << 10) + k0 + t];
    }
    __syncthreads();
    double rs = 1.0 / sd[b];
    int kl = t & 63;
    int k = k0 + kl;
    double dv = dgl[kl], wk = wls[kl];
    for (int pass = 0; pass < 16; pass++) {
        int jl = (t >> 6) + pass * 4;
        int j = j0 + jl;
        long idx = ((long)(b << 10) + j) * KD + k;
        double a = (double)A[idx];
        double out;
        if (k == 0)      out = (j == 0) ? 0.0 : a * vls[jl] * rs;
        else if (j == 0) out = a * dv;
        else             out = a * (dv - Tt[kl][jl] + wk * vls[jl] * rs);
        A[idx] = (float)out;
    }
}

// ---------- a_ki output (transpose + d0 first column) ----------
__global__ void k_aki(const float* __restrict__ A, const float* __restrict__ d0, float* __restrict__ out) {
    __shared__ float T[64][65];
    int b = blockIdx.z;
    int i0 = blockIdx.y * 64;
    int k0 = blockIdx.x * 64;
    const float* Ab = A + (long)b * KD * KD;
    int t = threadIdx.x;
    for (int i = t; i < 64 * 64; i += 256) {
        int r = i / 64, c = i % 64;
        T[r][c] = Ab[(long)(i0 + r) * KD + k0 + c];
    }
    __syncthreads();
    float* ob = out + (long)b * KD * (KD + 1);
    int iloc = t % 64, kl0 = (t / 64) * 16;
    for (int kk = kl0; kk < kl0 + 16; kk++) {
        int kg = k0 + kk;
        ob[(long)kg * (KD + 1) + 1 + i0 + iloc] = T[iloc][kk];
    }
    if (blockIdx.y == 0 && t < 64) {
        int kg = k0 + t;
        ob[(long)kg * (KD + 1)] = d0[b * KD + kg];
    }
}

// ---------- si = a_ik^T @ e_i + d0 (x) exparam  (128x64 tiles, grid (8,6,BB)) ----------
__global__ __launch_bounds__(256, 2)
void k_si64(const float* __restrict__ Aik, const float* __restrict__ E,
            const float* __restrict__ d0, const float* __restrict__ expar,
            float* __restrict__ Si) {
    __shared__ float As[16][132];
    __shared__ float Bs[16][68];
    int b = blockIdx.z;
    int m0 = blockIdx.x * 128;   // k
    int n0 = blockIdx.y * 64;    // s
    const float* Ab = Aik + (long)b * KD * KD;
    const float* Eb = E + (long)b * KD * SS;
    int t = threadIdx.x, ty = t / 16, tx = t % 16;
    int lb_r = t / 16, lb_c = (t % 16) * 4;
    float acc[8][4] = {};
    for (int j0 = 0; j0 < KD; j0 += 16) {
        float4 a0 = *(const float4*)&Ab[(long)(j0 + lb_r) * KD + m0 + lb_c];
        float4 a1 = *(const float4*)&Ab[(long)(j0 + lb_r) * KD + m0 + 64 + lb_c];
        float4 b0 = *(const float4*)&Eb[(long)(j0 + lb_r) * SS + n0 + lb_c];
        __syncthreads();
        *(float4*)&As[lb_r][lb_c] = a0;
        *(float4*)&As[lb_r][64 + lb_c] = a1;
        *(float4*)&Bs[lb_r][lb_c] = b0;
        __syncthreads();
        mac16n(acc, As, Bs, ty, tx);
    }
#pragma unroll
    for (int i = 0; i < 8; i++) {
        int row = m0 + (i < 4 ? ty * 4 + i : 64 + ty * 4 + i - 4);
        float dr = d0[b * KD + row];
        float4 o0;
        float* p0 = &o0.x;
#pragma unroll
        for (int j = 0; j < 4; j++)
            p0[j] = acc[i][j] + dr * expar[n0 + tx * 4 + j];
        *(float4*)&Si[((long)b * KD + row) * SS + n0 + tx * 4] = o0;
    }
}

// ---------- ci = a_ik @ e_i  (128x64 tiles, grid (8,6,BB)) ----------
__global__ __launch_bounds__(256, 2)
void k_ci64(const float* __restrict__ Aik, const float* __restrict__ E, float* __restrict__ Ci) {
    __shared__ float As[16][132];
    __shared__ float Bs[16][68];
    int b = blockIdx.z;
    int m0 = blockIdx.x * 128;
    int n0 = blockIdx.y * 64;
    const float* Ab = Aik + (long)b * KD * KD;
    const float* Eb = E + (long)b * KD * SS;
    int t = threadIdx.x, ty = t / 16, tx = t % 16;
    int la_r = t / 4, la_c = (t % 4) * 4;
    int lb_r = t / 16, lb_c = (t % 16) * 4;
    float acc[8][4] = {};
    for (int k0 = 0; k0 < KD; k0 += 16) {
        float4 a0 = *(const float4*)&Ab[(long)(m0 + la_r) * KD + k0 + la_c];
        float4 a1 = *(const float4*)&Ab[(long)(m0 + 64 + la_r) * KD + k0 + la_c];
        float4 b0 = *(const float4*)&Eb[(long)(k0 + lb_r) * SS + n0 + lb_c];
        __syncthreads();
        storeA_t(As, a0, a1, la_r, la_c);
        *(float4*)&Bs[lb_r][lb_c] = b0;
        __syncthreads();
        mac16n(acc, As, Bs, ty, tx);
    }
#pragma unroll
    for (int i = 0; i < 8; i++) {
        int row = m0 + (i < 4 ? ty * 4 + i : 64 + ty * 4 + i - 4);
        *(float4*)&Ci[((long)b * KD + row) * SS + n0 + tx * 4] = *(float4*)&acc[i][0];
    }
}

// ---------- r_i = tanh([e,si,ci] @ Wr + br)  (128x64 tiles, grid (128,6)) ----------
__global__ __launch_bounds__(256, 2)
void k_ri64(const float* __restrict__ E, const float* __restrict__ Si, const float* __restrict__ Ci,
            const float* __restrict__ Wr, const float* __restrict__ br, float* __restrict__ out) {
    __shared__ float As[16][132];
    __shared__ float Bs[16][68];
    int m0 = blockIdx.x * 128, n0 = blockIdx.y * 64;
    int t = threadIdx.x, ty = t / 16, tx = t % 16;
    int la_r = t / 4, la_c = (t % 4) * 4;
    int lb_r = t / 16, lb_c = (t % 16) * 4;
    float acc[8][4] = {};
    const float* srcs[3] = {E, Si, Ci};
    for (int seg = 0; seg < 3; seg++) {
        const float* Sp = srcs[seg];
        for (int k0 = 0; k0 < SS; k0 += 16) {
            float4 a0 = *(const float4*)&Sp[(long)(m0 + la_r) * SS + k0 + la_c];
            float4 a1 = *(const float4*)&Sp[(long)(m0 + 64 + la_r) * SS + k0 + la_c];
            float4 b0 = *(const float4*)&Wr[(long)(seg * SS + k0 + lb_r) * SS + n0 + lb_c];
            __syncthreads();
            storeA_t(As, a0, a1, la_r, la_c);
            *(float4*)&Bs[lb_r][lb_c] = b0;
            __syncthreads();
            mac16n(acc, As, Bs, ty, tx);
        }
    }
#pragma unroll
    for (int i = 0; i < 8; i++) {
        int row = m0 + (i < 4 ? ty * 4 + i : 64 + ty * 4 + i - 4);
        float4 o0;
        float* p0 = &o0.x;
#pragma unroll
        for (int j = 0; j < 4; j++)
            p0[j] = tanhf(acc[i][j] + br[n0 + tx * 4 + j]);
        *(float4*)&out[(long)row * SS + n0 + tx * 4] = o0;
    }
}

extern "C" void kernel_launch(void* const* d_in, const int* in_sizes, int n_in,
                              void* d_out, int out_size, void* d_ws, size_t ws_size,
                              hipStream_t stream) {
    const float* x     = (const float*)d_in[0];
    const float* Wp_w  = (const float*)d_in[1];
    const float* Wp_b  = (const float*)d_in[2];
    const float* Wc_w  = (const float*)d_in[3];
    const float* Wc_b  = (const float*)d_in[4];
    const float* fi_w  = (const float*)d_in[5];
    const float* Wa_w  = (const float*)d_in[6];
    const float* expar = (const float*)d_in[7];
    const float* Wr_w  = (const float*)d_in[8];
    const float* Wr_b  = (const float*)d_in[9];

    float* ws = (float*)d_ws;
    // Region R (offset 23,068,672, span 33,554,432 f32 = 128 MB) is time-multiplexed:
    // early {di/tt, uj, uk}; mid: Td (fp64 padded T matrix -> Tinv); late: {si, ci}.
    float*  A    = ws;                               // 16,777,216 f32 (S -> A -> a_ik)
    float*  ei   = ws + 16777216;                    //  6,291,456 f32
    float*  R    = ws + 23068672;
    float*  di   = R;
    float*  uj   = R + 6291456;
    float*  uk   = R + 12582912;
    float*  tt   = di;
    double* Td   = (double*)R;                       // 16,777,216 doubles = 128 MB
    float*  sbuf = R;                                // after Td dead
    float*  cbuf = R + 6291456;
    double* Ftd  = (double*)(ws + 56623104);         // 1,048,576 doubles = 8 MB
    float*  g    = ws + 58720256;                    // 16,384
    float*  mcol = ws + 58736640;                    // 16,384
    float*  fi   = ws + 58753024;                    // 16,384
    float*  d0   = ws + 58769408;                    // 16,384
    double* csd  = (double*)(ws + 58785792);         // 16,384 doubles
    double* wd   = (double*)(ws + 58818560);         // 16,384 doubles
    double* vd   = (double*)(ws + 58851328);         // 16,384 doubles
    double* dgvd = (double*)(ws + 58884096);         // 16,384 doubles
    double* a0c  = (double*)(ws + 58916864);         // 16,384 doubles
    double* frc  = (double*)(ws + 58949632);         // 16,384 doubles
    double* sd   = (double*)(ws + 58982400);         // 16 doubles; end ~236 MB

    float* r_out   = (float*)d_out;
    float* aki_out = r_out + (long)BB * KD * SS;
    // aki output region (64 MB) is dead until k_aki: borrow 1 MB as colmax scratch.
    float* pmax    = aki_out;                        // 16 * 16384 f32

    k_prep<<<BB * KD * SS / 256, 256, 0, stream>>>(x, di, ei);
    k_gemm_pc<<<dim3(128, 6), 256, 0, stream>>>(di, Wp_w, Wp_b, Wc_w, Wc_b, uj, uk);
    k_firaw<<<BB * KD / 4, 256, 0, stream>>>(di, fi_w, g);
    k_gemm64<false, false><<<dim3(128, 6), 256, 0, stream>>>(uj, Wa_w, nullptr, tt, BB * KD, SS, SS);
    k_fjk16<<<dim3(8, 8, BB), 256, 0, stream>>>(tt, uk, A);
    k_colmax1<<<dim3(BB * KD / 256, 16), 256, 0, stream>>>(A, pmax);
    k_colmax2<<<BB * KD / 256, 256, 0, stream>>>(pmax, g, mcol, fi, csd);
    k_expA_sum<<<dim3(16, 16, BB), 256, 0, stream>>>(A, mcol, csd);
    k_buildT<<<BB * KD * KD / 256, 256, 0, stream>>>(A, csd, Td);

    for (int s = 0; s < KD / NBLK; s++) {
        int kb = s * NBLK;
        k_diagsave_d<<<BB * KD * NBLK / 256 + BB, 256, 0, stream>>>(Td, Ftd, kb);
        k_rowcol_d<<<dim3((KD - NBLK) / 32, BB), 256, 0, stream>>>(Td, kb);
        k_elim_d<<<dim3(8, 16, BB), 256, 0, stream>>>(Td, Ftd, kb);
    }

    k_compact<<<BB * KD / 256, 256, 0, stream>>>(A, fi, a0c, frc, vd, sd);
    k_w<<<BB * KD / 4, 256, 0, stream>>>(Td, a0c, frc, wd, sd);
    k_v<<<dim3(4, 8, BB), 256, 0, stream>>>(Td, frc, vd);
    k_dgv<<<BB * KD / 256, 256, 0, stream>>>(Td, wd, vd, sd, fi, dgvd, d0);
    k_aik2<<<dim3(16, 16, BB), 256, 0, stream>>>(A, Td, wd, vd, dgvd, sd);
    k_aki<<<dim3(16, 16, BB), 256, 0, stream>>>(A, d0, aki_out);
    k_si64<<<dim3(8, 6, BB), 256, 0, stream>>>(A, ei, d0, expar, sbuf);
    k_ci64<<<dim3(8, 6, BB), 256, 0, stream>>>(A, ei, cbuf);
    k_ri64<<<dim3(128, 6), 256, 0, stream>>>(ei, sbuf, cbuf, Wr_w, Wr_b, r_out);
}

// Round 9
// 4257.545 us; speedup vs baseline: 1.0596x; 1.0521x over previous
//
#include <hip/hip_runtime.h>

#define BB 16
#define KD 1024
#define DD 768
#define SS 384
#define HH 192
#define NBLK 64

// ================= 128x128xBK16 fp32 GEMM micro-core (mac16) =================
// 256 threads, 8x8 acc per thread, rows {ty*4, 64+ty*4}, cols {tx*4, 64+tx*4}.
__device__ __forceinline__ void mac16(float (&acc)[8][8], const float (*As)[132], const float (*Bs)[132],
                                      int ty, int tx) {
#pragma unroll
    for (int kk = 0; kk < 16; kk++) {
        float a[8], b[8];
        *(float4*)&a[0] = *(const float4*)&As[kk][ty * 4];
        *(float4*)&a[4] = *(const float4*)&As[kk][64 + ty * 4];
        *(float4*)&b[0] = *(const float4*)&Bs[kk][tx * 4];
        *(float4*)&b[4] = *(const float4*)&Bs[kk][64 + tx * 4];
#pragma unroll
        for (int i = 0; i < 8; i++)
#pragma unroll
            for (int j = 0; j < 8; j++)
                acc[i][j] += a[i] * b[j];
    }
}

// ================= 64x128xBK16 fp32 micro-core (mac16m) =================
// 256 threads, 4x8 acc: rows ty*4+i (ty=t>>4), cols {tx*4+j, 64+tx*4+j} (tx=t&15).
// 768-block grids -> 3 blocks/CU, no tail; A-panels read only 3x (vs 6x for 128x64).
__device__ __forceinline__ void mac16m(float (&acc)[4][8], const float (*As)[68], const float (*Bs)[132],
                                       int ty, int tx) {
#pragma unroll
    for (int kk = 0; kk < 16; kk++) {
        float a[4], b[8];
        *(float4*)&a[0] = *(const float4*)&As[kk][ty * 4];
        *(float4*)&b[0] = *(const float4*)&Bs[kk][tx * 4];
        *(float4*)&b[4] = *(const float4*)&Bs[kk][64 + tx * 4];
#pragma unroll
        for (int i = 0; i < 4; i++)
#pragma unroll
            for (int j = 0; j < 8; j++)
                acc[i][j] += a[i] * b[j];
    }
}

// transpose-store an A-style tile (row-major MxK source chunk) into As[k][m]
__device__ __forceinline__ void storeA_t(float (*As)[132], const float4& v0, const float4& v1,
                                         int la_r, int la_c) {
    As[la_c + 0][la_r] = v0.x; As[la_c + 1][la_r] = v0.y;
    As[la_c + 2][la_r] = v0.z; As[la_c + 3][la_r] = v0.w;
    As[la_c + 0][64 + la_r] = v1.x; As[la_c + 1][64 + la_r] = v1.y;
    As[la_c + 2][64 + la_r] = v1.z; As[la_c + 3][64 + la_r] = v1.w;
}

// 64-row variant: one float4 per thread
__device__ __forceinline__ void storeA_t64(float (*As)[68], const float4& v0, int la_r, int la_c) {
    As[la_c + 0][la_r] = v0.x; As[la_c + 1][la_r] = v0.y;
    As[la_c + 2][la_r] = v0.z; As[la_c + 3][la_r] = v0.w;
}

// ---------- split x into e_i / d_i ----------
__global__ void k_prep(const float* __restrict__ x, float* __restrict__ di, float* __restrict__ ei) {
    int idx = blockIdx.x * 256 + threadIdx.x;       // over BB*KD*SS
    int s = idx % SS;
    long bk = idx / SS;
    const float* xr = x + bk * DD;
    ei[idx] = xr[s < HH ? s : s + HH];
    di[idx] = xr[s < HH ? s + HH : s + 2 * HH];
}

// ---------- generic fp32 NN GEMM, 64x128 tile: C = act(A[M,Kd] @ B[Kd,N] + bias) ----------
template<bool BIAS, bool TANH>
__global__ __launch_bounds__(256, 2)
void k_gemm64m(const float* __restrict__ A, const float* __restrict__ Bw,
               const float* __restrict__ bias, float* __restrict__ C,
               int M, int N, int Kd) {
    __shared__ float As[16][68];
    __shared__ float Bs[16][132];
    int m0 = blockIdx.x * 64, n0 = blockIdx.y * 128;
    int t = threadIdx.x;
    int ty = t >> 4, tx = t & 15;
    int la_r = t / 4, la_c = (t % 4) * 4;
    int lb_r = t >> 4, lb_c = (t & 15) * 4;
    float acc[4][8] = {};
    for (int k0 = 0; k0 < Kd; k0 += 16) {
        float4 a0 = *(const float4*)&A[(long)(m0 + la_r) * Kd + k0 + la_c];
        float4 b0 = *(const float4*)&Bw[(long)(k0 + lb_r) * N + n0 + lb_c];
        float4 b1 = *(const float4*)&Bw[(long)(k0 + lb_r) * N + n0 + 64 + lb_c];
        __syncthreads();
        storeA_t64(As, a0, la_r, la_c);
        *(float4*)&Bs[lb_r][lb_c] = b0;
        *(float4*)&Bs[lb_r][64 + lb_c] = b1;
        __syncthreads();
        mac16m(acc, As, Bs, ty, tx);
    }
#pragma unroll
    for (int i = 0; i < 4; i++) {
        int row = m0 + ty * 4 + i;
        float4 o0, o1;
        float* p0 = &o0.x; float* p1 = &o1.x;
#pragma unroll
        for (int j = 0; j < 4; j++) {
            float v = acc[i][j];
            if (BIAS) v += bias[n0 + tx * 4 + j];
            if (TANH) v = tanhf(v);
            p0[j] = v;
            float w = acc[i][j + 4];
            if (BIAS) w += bias[n0 + 64 + tx * 4 + j];
            if (TANH) w = tanhf(w);
            p1[j] = w;
        }
        *(float4*)&C[(long)row * N + n0 + tx * 4] = o0;
        *(float4*)&C[(long)row * N + n0 + 64 + tx * 4] = o1;
    }
}

// ---------- merged parent/child transforms: uj = tanh(di@Wp+bp), uk = tanh(di@Wc+bc) ----------
// grid (128, 6): y<3 -> {Wp,bp,uj}, else {Wc,bc,uk}. Same A tiles, one launch.
__global__ __launch_bounds__(256, 2)
void k_gemm_pc(const float* __restrict__ A, const float* __restrict__ Wp,
               const float* __restrict__ bp, const float* __restrict__ Wc,
               const float* __restrict__ bc, float* __restrict__ Uj, float* __restrict__ Uk) {
    __shared__ float As[16][132];
    __shared__ float Bs[16][132];
    bool first = blockIdx.y < 3;
    const float* Bw = first ? Wp : Wc;
    const float* bias = first ? bp : bc;
    float* C = first ? Uj : Uk;
    int m0 = blockIdx.x * 128, n0 = (blockIdx.y % 3) * 128;
    int t = threadIdx.x;
    int ty = t / 16, tx = t % 16;
    int la_r = t / 4, la_c = (t % 4) * 4;
    int lb_r = t / 16, lb_c = (t % 16) * 4;
    float acc[8][8] = {};
    for (int k0 = 0; k0 < SS; k0 += 16) {
        float4 a0 = *(const float4*)&A[(long)(m0 + la_r) * SS + k0 + la_c];
        float4 a1 = *(const float4*)&A[(long)(m0 + 64 + la_r) * SS + k0 + la_c];
        float4 b0 = *(const float4*)&Bw[(long)(k0 + lb_r) * SS + n0 + lb_c];
        float4 b1 = *(const float4*)&Bw[(long)(k0 + lb_r) * SS + n0 + 64 + lb_c];
        __syncthreads();
        storeA_t(As, a0, a1, la_r, la_c);
        *(float4*)&Bs[lb_r][lb_c] = b0;
        *(float4*)&Bs[lb_r][64 + lb_c] = b1;
        __syncthreads();
        mac16(acc, As, Bs, ty, tx);
    }
#pragma unroll
    for (int i = 0; i < 8; i++) {
        int row = m0 + (i < 4 ? ty * 4 + i : 64 + ty * 4 + i - 4);
        float4 o0, o1;
        float* p0 = &o0.x; float* p1 = &o1.x;
#pragma unroll
        for (int j = 0; j < 4; j++) {
            p0[j] = tanhf(acc[i][j] + bias[n0 + tx * 4 + j]);
            p1[j] = tanhf(acc[i][j + 4] + bias[n0 + 64 + tx * 4 + j]);
        }
        *(float4*)&C[(long)row * SS + n0 + tx * 4] = o0;
        *(float4*)&C[(long)row * SS + n0 + 64 + tx * 4] = o1;
    }
}

// ---------- batched NT GEMM: S[b,j,k] = sum_s T[b,j,s]*Uk[b,k,s]  (raw scores) ----------
__global__ __launch_bounds__(256, 2)
void k_fjk16(const float* __restrict__ T, const float* __restrict__ Uk, float* __restrict__ Sout) {
    __shared__ float As[16][132];
    __shared__ float Bs[16][132];
    int b = blockIdx.z;
    const float* Ab = T + (long)b * KD * SS;
    const float* Bb = Uk + (long)b * KD * SS;
    int m0 = blockIdx.x * 128, n0 = blockIdx.y * 128;
    int t = threadIdx.x;
    int ty = t / 16, tx = t % 16;
    int la_r = t / 4, la_c = (t % 4) * 4;
    float acc[8][8] = {};
    for (int k0 = 0; k0 < SS; k0 += 16) {
        float4 a0 = *(const float4*)&Ab[(long)(m0 + la_r) * SS + k0 + la_c];
        float4 a1 = *(const float4*)&Ab[(long)(m0 + 64 + la_r) * SS + k0 + la_c];
        float4 b0 = *(const float4*)&Bb[(long)(n0 + la_r) * SS + k0 + la_c];
        float4 b1 = *(const float4*)&Bb[(long)(n0 + 64 + la_r) * SS + k0 + la_c];
        __syncthreads();
        storeA_t(As, a0, a1, la_r, la_c);
        storeA_t(Bs, b0, b1, la_r, la_c);
        __syncthreads();
        mac16(acc, As, Bs, ty, tx);
    }
#pragma unroll
    for (int i = 0; i < 8; i++) {
        int row = m0 + (i < 4 ? ty * 4 + i : 64 + ty * 4 + i - 4);
        *(float4*)&Sout[((long)b * KD + row) * KD + n0 + tx * 4] = *(float4*)&acc[i][0];
        *(float4*)&Sout[((long)b * KD + row) * KD + n0 + 64 + tx * 4] = *(float4*)&acc[i][4];
    }
}

// ---------- raw root logit g = d_i . fi_w ----------
__global__ void k_firaw(const float* __restrict__ di, const float* __restrict__ fiw, float* __restrict__ g) {
    int w = (blockIdx.x * 256 + threadIdx.x) / 64;
    int lane = threadIdx.x % 64;
    if (w >= BB * KD) return;
    const float* dr = di + (long)w * SS;
    float s = 0.f;
    for (int i = lane; i < SS; i += 64) s += dr[i] * fiw[i];
    for (int off = 32; off; off >>= 1) s += __shfl_down(s, off);
    if (lane == 0) g[w] = s;
}

// ---------- per-column max, stage 1: partial over 64-row j-chunks ----------
__global__ void k_colmax1(const float* __restrict__ S, float* __restrict__ pmax) {
    int idx = blockIdx.x * 256 + threadIdx.x;   // BB*KD
    int jt = blockIdx.y;                        // 16 j-chunks of 64
    int b = idx >> 10, k = idx & (KD - 1);
    const float* Sb = S + (long)b * KD * KD;
    float m = -3.4e38f;
    for (int j = jt * 64; j < jt * 64 + 64; j++) {
        float v = Sb[(long)j * KD + k];
        m = fmaxf(m, (j == k) ? -3.4e38f : v);
    }
    pmax[((long)jt << 14) + idx] = m;
}

// ---------- per-column max, stage 2: reduce partials + fold g; fi = exp(g-m); zero csd ----------
__global__ void k_colmax2(const float* __restrict__ pmax, const float* __restrict__ g,
                          float* __restrict__ mcol, float* __restrict__ fi, double* __restrict__ csd) {
    int idx = blockIdx.x * 256 + threadIdx.x;   // BB*KD
    float gv = g[idx];
    float m = gv;
    for (int jt = 0; jt < 16; jt++) m = fmaxf(m, pmax[((long)jt << 14) + idx]);
    mcol[idx] = m;
    fi[idx] = expf(gv - m);
    csd[idx] = 0.0;                             // prepare for fused col-sum atomics
}

// ---------- A = exp(S - m_col) (diag zeroed, in place) + fused fp64 column sums ----------
// 64x64 tile per block; per-column partial reduced in LDS, one atomicAdd per col per j-tile.
__global__ __launch_bounds__(256)
void k_expA_sum(float* __restrict__ S, const float* __restrict__ mcol, double* __restrict__ csd) {
    __shared__ double red[4][64];
    int b = blockIdx.z, jt = blockIdx.y, kt = blockIdx.x;
    int t = threadIdx.x;
    int tc = t & 63, tg = t >> 6;               // col in tile, row-group (4x16 rows)
    int kg = kt * 64 + tc;
    float mc = mcol[(b << 10) + kg];
    float* Sb = S + ((long)b << 20);
    double s = 0.0;
    for (int rr = 0; rr < 16; rr++) {
        int j = jt * 64 + tg * 16 + rr;
        long a = ((long)j << 10) + kg;
        float v = (j == kg) ? 0.f : expf(Sb[a] - mc);
        Sb[a] = v;
        s += (double)v;
    }
    red[tg][tc] = s;
    __syncthreads();
    if (tg == 0) {
        double tot = red[0][tc] + red[1][tc] + red[2][tc] + red[3][tc];
        atomicAdd(&csd[(b << 10) + kg], tot);
    }
}

// ---------- build padded T~ (fp64): T[i][j] = L[1+i][1+j] for i,j<1023; identity pad at 1023 ----------
__global__ void k_buildT(const float* __restrict__ A, const double* __restrict__ csd, double* __restrict__ Td) {
    long idx = (long)blockIdx.x * 256 + threadIdx.x;  // BB*KD*KD
    int j = idx & (KD - 1);
    int i = (int)(idx >> 10) & (KD - 1);
    int b = (int)(idx >> 20);
    double v;
    if (i == KD - 1 || j == KD - 1) v = (i == j) ? 1.0 : 0.0;
    else if (i == j) v = csd[(b << 10) + j + 1];
    else v = -(double)A[((long)b << 20) + ((long)(i + 1) << 10) + (j + 1)];
    Td[idx] = v;
}

// ---------- GJ step (fp64): fused {savecol || diag} ----------
// savecol blocks copy the pivot-column block M[:, kb:kb+64] to Ft; diag blocks
// invert the 64x64 diagonal block in LDS. Independent: diag writes only rows
// kb..kb+63 of the pivot column, and those Ft rows (it==kt) are skipped by
// k_elim_d, so concurrent/torn reads of that sub-block are never consumed.
__global__ __launch_bounds__(256)
void k_diagsave_d(double* __restrict__ M, double* __restrict__ Ft, int kb) {
    __shared__ double P[NBLK][NBLK + 1];
    __shared__ double rowbuf[NBLK];
    const int nsave = BB * KD * NBLK / 256;   // 4096 copy blocks
    if ((int)blockIdx.x < nsave) {
        int idx = blockIdx.x * 256 + threadIdx.x;     // BB*KD*NBLK
        int c = idx % NBLK;
        int rk = idx / NBLK;
        int r = rk % KD, b = rk / KD;
        Ft[idx] = M[((long)b * KD + r) * KD + kb + c];
        return;
    }
    int b = blockIdx.x - nsave;
    double* Mb = M + (long)b * KD * KD;
    int t = threadIdx.x;
    for (int i = t; i < NBLK * NBLK; i += 256)
        P[i / NBLK][i % NBLK] = Mb[(long)(kb + i / NBLK) * KD + kb + i % NBLK];
    __syncthreads();
    int mi = t & 63;
    int c0 = (t >> 6) * 16;
    for (int kk = 0; kk < NBLK; kk++) {
        double p = 1.0 / P[kk][kk];
        double F = P[mi][kk];
        if (t < 64) rowbuf[t] = P[kk][t] * p;
        __syncthreads();
        if (mi == kk) {
            for (int c = c0; c < c0 + 16; c++)
                P[mi][c] = (c == kk) ? p : rowbuf[c];
        } else {
            for (int c = c0; c < c0 + 16; c++)
                P[mi][c] = (c == kk) ? (-F * p) : (P[mi][c] - F * rowbuf[c]);
        }
        __syncthreads();
    }
    for (int i = t; i < NBLK * NBLK; i += 256)
        Mb[(long)(kb + i / NBLK) * KD + kb + i % NBLK] = P[i / NBLK][i % NBLK];
}

// ---------- GJ step (fp64): pivot block-row update  M[k, strip] = Dinv @ M[k, strip] ----------
__global__ __launch_bounds__(256)
void k_rowcol_d(double* __restrict__ M, int kb) {
    __shared__ double Ps[NBLK][NBLK + 1];   // Dinv[r][k]
    __shared__ double Ts[NBLK][33];         // R[k][c] (32-col strip)
    int b = blockIdx.y;
    int js = blockIdx.x;
    int j0 = js * 32 + (js * 32 >= kb ? NBLK : 0);   // skip pivot tile
    double* Mb = M + (long)b * KD * KD;
    int t = threadIdx.x;
    for (int i = t; i < NBLK * NBLK; i += 256)
        Ps[i >> 6][i & 63] = Mb[(long)(kb + (i >> 6)) * KD + kb + (i & 63)];
    for (int i = t; i < NBLK * 32; i += 256) {
        int r = i >> 5, c = i & 31;
        Ts[r][c] = Mb[(long)(kb + r) * KD + j0 + c];
    }
    __syncthreads();
    int tr4 = (t >> 4) * 4;        // 16 row-groups of 4
    int tc2 = (t & 15) * 2;        // 16 col-pairs
    double acc[4][2] = {};
    for (int kk = 0; kk < NBLK; kk++) {
        double bv0 = Ts[kk][tc2], bv1 = Ts[kk][tc2 + 1];
#pragma unroll
        for (int i = 0; i < 4; i++) {
            double a = Ps[tr4 + i][kk];
            acc[i][0] += a * bv0;
            acc[i][1] += a * bv1;
        }
    }
#pragma unroll
    for (int i = 0; i < 4; i++) {
        Mb[(long)(kb + tr4 + i) * KD + j0 + tc2]     = acc[i][0];
        Mb[(long)(kb + tr4 + i) * KD + j0 + tc2 + 1] = acc[i][1];
    }
}

// ---------- GJ step (fp64): trailing elimination + pivot-column update ----------
__global__ __launch_bounds__(256, 2)
void k_elim_d(double* __restrict__ M, const double* __restrict__ Ft, int kb) {
    __shared__ double Fs[16][NBLK + 2];    // Fs[kcol][row]
    __shared__ double Rs[16][132];         // Rs[krow][col]
    int b = blockIdx.z;
    int it = blockIdx.y;
    int kt = kb / NBLK;
    if (it == kt) return;
    int i0 = it * NBLK;
    int j0 = blockIdx.x * 128;
    double* Mb = M + (long)b * KD * KD;
    const double* Fb = Ft + ((long)b * KD + i0) * NBLK;
    const double* Rrow = Mb + (long)kb * KD;
    int t = threadIdx.x, ty = t >> 4, tx = t & 15;
    double acc[4][8] = {};
    for (int kc = 0; kc < NBLK; kc += 16) {
        __syncthreads();
        for (int i = t; i < 16 * NBLK; i += 256) {
            int r = i >> 4, c = i & 15;
            Fs[c][r] = Fb[(long)r * NBLK + kc + c];
        }
        for (int i = t; i < 16 * 128; i += 256) {
            int r = i >> 7, c = i & 127;
            Rs[r][c] = Rrow[(long)(kc + r) * KD + j0 + c];
        }
        __syncthreads();
#pragma unroll
        for (int kk = 0; kk < 16; kk++) {
            double a[4], bv[8];
#pragma unroll
            for (int i = 0; i < 4; i++) a[i] = Fs[kk][ty * 4 + i];
#pragma unroll
            for (int p = 0; p < 4; p++) {
                bv[p * 2 + 0] = Rs[kk][p * 32 + tx * 2 + 0];
                bv[p * 2 + 1] = Rs[kk][p * 32 + tx * 2 + 1];
            }
#pragma unroll
            for (int i = 0; i < 4; i++)
#pragma unroll
                for (int j = 0; j < 8; j++)
                    acc[i][j] += a[i] * bv[j];
        }
    }
#pragma unroll
    for (int i = 0; i < 4; i++) {
        int r = i0 + ty * 4 + i;
#pragma unroll
        for (int p = 0; p < 4; p++) {
            int c = j0 + p * 32 + tx * 2;
            bool piv = (c >= kb && c < kb + NBLK);
            double b0 = piv ? 0.0 : Mb[(long)r * KD + c];
            double b1 = piv ? 0.0 : Mb[(long)r * KD + c + 1];
            Mb[(long)r * KD + c]     = b0 - acc[i][p * 2 + 0];
            Mb[(long)r * KD + c + 1] = b1 - acc[i][p * 2 + 1];
        }
    }
}

// ---------- compact a0/fr (shifted, zero pad); zero vd ----------
__global__ void k_compact(const float* __restrict__ A, const float* __restrict__ fi,
                          double* __restrict__ a0c, double* __restrict__ frc,
                          double* __restrict__ vd) {
    int idx = blockIdx.x * 256 + threadIdx.x;   // BB*KD
    int b = idx >> 10, i = idx & (KD - 1);
    a0c[idx] = (i < KD - 1) ? (double)A[((long)b << 20) + ((long)(i + 1) << 10)] : 0.0;
    frc[idx] = (i < KD - 1) ? (double)fi[(b << 10) + i + 1] : 0.0;
    vd[idx] = 0.0;
}

// ---------- w = Tinv @ a0  (wave per row; pure — no contended atomics) ----------
__global__ void k_w(const double* __restrict__ Td, const double* __restrict__ a0c, double* __restrict__ wd) {
    int w = (blockIdx.x * 256 + threadIdx.x) >> 6;   // BB*KD waves
    int lane = threadIdx.x & 63;
    int b = w >> 10, r = w & (KD - 1);
    const double* Tb = Td + ((long)b << 20);
    const double* ab = a0c + (b << 10);
    double s = 0.0;
    for (int j = lane; j < KD; j += 64) s += Tb[((long)r << 10) + j] * ab[j];
    for (int off = 32; off; off >>= 1) s += __shfl_down(s, off);
    if (lane == 0) wd[(b << 10) + r] = s;
}

// ---------- s = f0 + fr . w  (block per batch; LDS tree reduce — no atomic convoy) ----------
// s = f0 + v.a0 = f0 + fr^T Tinv a0 = f0 + fr.w (same bilinear form)
__global__ void k_s2(const double* __restrict__ wd, const double* __restrict__ frc,
                     const float* __restrict__ fi, double* __restrict__ sd) {
    __shared__ double red[256];
    int b = blockIdx.x;
    int t = threadIdx.x;
    double s = 0.0;
    for (int j = t; j < KD; j += 256) s += frc[(b << 10) + j] * wd[(b << 10) + j];
    red[t] = s;
    __syncthreads();
    for (int off = 128; off; off >>= 1) {
        if (t < off) red[t] += red[t + off];
        __syncthreads();
    }
    if (t == 0) sd[b] = red[0] + (double)fi[b << 10];
}

// ---------- v = fr^T @ Tinv  (split-K over i-chunks, fp64 atomics: 8/address) ----------
__global__ void k_v(const double* __restrict__ Td, const double* __restrict__ frc, double* __restrict__ vd) {
    int b = blockIdx.z;
    int j = blockIdx.x * 256 + threadIdx.x;
    int i0 = blockIdx.y * 128;
    const double* Tb = Td + ((long)b << 20);
    const double* fb = frc + (b << 10);
    double s = 0.0;
    for (int i = i0; i < i0 + 128; i++) s += fb[i] * Tb[((long)i << 10) + j];
    atomicAdd(&vd[(b << 10) + j], s);
}

// ---------- dgv[k] = Linv[k][k], d0[k] = f_k * Linv[k][0] ----------
__global__ void k_dgv(const double* __restrict__ Td, const double* __restrict__ wd,
                      const double* __restrict__ vd, const double* __restrict__ sd,
                      const float* __restrict__ fi, double* __restrict__ dgvd, float* __restrict__ d0) {
    int idx = blockIdx.x * 256 + threadIdx.x;  // BB*KD
    int b = idx >> 10, k = idx & (KD - 1);
    double rs = 1.0 / sd[b];
    if (k == 0) {
        dgvd[idx] = rs;
        d0[idx] = (float)((double)fi[idx] * rs);
    } else {
        int i = k - 1;
        dgvd[idx] = Td[((long)b << 20) + ((long)i << 10) + i] - wd[(b << 10) + i] * vd[(b << 10) + i] * rs;
        d0[idx] = (float)((double)fi[idx] * wd[(b << 10) + i] * rs);
    }
}

// ---------- a_ik in place over A via bordered-inverse algebra ----------
__global__ __launch_bounds__(256)
void k_aik2(float* __restrict__ A, const double* __restrict__ Td,
            const double* __restrict__ wd, const double* __restrict__ vd,
            const double* __restrict__ dgvd, const double* __restrict__ sd) {
    __shared__ double Tt[64][65];
    __shared__ double wls[64], vls[64], dgl[64];
    int b = blockIdx.z;
    int k0 = blockIdx.x * 64, j0 = blockIdx.y * 64;
    const double* Tb = Td + ((long)b << 20);
    int t = threadIdx.x;
    for (int i = t; i < 64 * 64; i += 256) {
        int kl = i >> 6, jl = i & 63;
        int kk = k0 + kl - 1, jj = j0 + jl - 1;
        Tt[kl][jl] = (kk >= 0 && jj >= 0) ? Tb[((long)kk << 10) + jj] : 0.0;
    }
    if (t < 64) {
        wls[t] = (k0 + t >= 1) ? wd[(b << 10) + k0 + t - 1] : 0.0;
        vls[t] = (j0 + t >= 1) ? vd[(b << 10) + j0 + t - 1] : 0.0;
        dgl[t] = dgvd[(b << 10) + k0 + t];
    }
    __syncthreads();
    double rs = 1.0 / sd[b];
    int kl = t & 63;
    int k = k0 + kl;
    double dv = dgl[kl], wk = wls[kl];
    for (int pass = 0; pass < 16; pass++) {
        int jl = (t >> 6) + pass * 4;
        int j = j0 + jl;
        long idx = ((long)(b << 10) + j) * KD + k;
        double a = (double)A[idx];
        double out;
        if (k == 0)      out = (j == 0) ? 0.0 : a * vls[jl] * rs;
        else if (j == 0) out = a * dv;
        else             out = a * (dv - Tt[kl][jl] + wk * vls[jl] * rs);
        A[idx] = (float)out;
    }
}

// ---------- a_ki output (transpose + d0 first column) ----------
__global__ void k_aki(const float* __restrict__ A, const float* __restrict__ d0, float* __restrict__ out) {
    __shared__ float T[64][65];
    int b = blockIdx.z;
    int i0 = blockIdx.y * 64;
    int k0 = blockIdx.x * 64;
    const float* Ab = A + (long)b * KD * KD;
    int t = threadIdx.x;
    for (int i = t; i < 64 * 64; i += 256) {
        int r = i / 64, c = i % 64;
        T[r][c] = Ab[(long)(i0 + r) * KD + k0 + c];
    }
    __syncthreads();
    float* ob = out + (long)b * KD * (KD + 1);
    int iloc = t % 64, kl0 = (t / 64) * 16;
    for (int kk = kl0; kk < kl0 + 16; kk++) {
        int kg = k0 + kk;
        ob[(long)kg * (KD + 1) + 1 + i0 + iloc] = T[iloc][kk];
    }
    if (blockIdx.y == 0 && t < 64) {
        int kg = k0 + t;
        ob[(long)kg * (KD + 1)] = d0[b * KD + kg];
    }
}

// ---------- si = a_ik^T @ e_i + d0 (x) exparam  (64x128 tiles, grid (16,3,BB)) ----------
__global__ __launch_bounds__(256, 2)
void k_si64m(const float* __restrict__ Aik, const float* __restrict__ E,
             const float* __restrict__ d0, const float* __restrict__ expar,
             float* __restrict__ Si) {
    __shared__ float As[16][68];    // As[j][k_local] — source already reduction-major
    __shared__ float Bs[16][132];
    int b = blockIdx.z;
    int m0 = blockIdx.x * 64;    // k
    int n0 = blockIdx.y * 128;   // s
    const float* Ab = Aik + (long)b * KD * KD;
    const float* Eb = E + (long)b * KD * SS;
    int t = threadIdx.x, ty = t >> 4, tx = t & 15;
    int lb_r = t >> 4, lb_c = (t & 15) * 4;
    float acc[4][8] = {};
    for (int j0 = 0; j0 < KD; j0 += 16) {
        float4 a0 = *(const float4*)&Ab[(long)(j0 + lb_r) * KD + m0 + lb_c];
        float4 b0 = *(const float4*)&Eb[(long)(j0 + lb_r) * SS + n0 + lb_c];
        float4 b1 = *(const float4*)&Eb[(long)(j0 + lb_r) * SS + n0 + 64 + lb_c];
        __syncthreads();
        *(float4*)&As[lb_r][lb_c] = a0;
        *(float4*)&Bs[lb_r][lb_c] = b0;
        *(float4*)&Bs[lb_r][64 + lb_c] = b1;
        __syncthreads();
        mac16m(acc, As, Bs, ty, tx);
    }
#pragma unroll
    for (int i = 0; i < 4; i++) {
        int row = m0 + ty * 4 + i;
        float dr = d0[b * KD + row];
        float4 o0, o1;
        float* p0 = &o0.x; float* p1 = &o1.x;
#pragma unroll
        for (int j = 0; j < 4; j++) {
            p0[j] = acc[i][j] + dr * expar[n0 + tx * 4 + j];
            p1[j] = acc[i][j + 4] + dr * expar[n0 + 64 + tx * 4 + j];
        }
        *(float4*)&Si[((long)b * KD + row) * SS + n0 + tx * 4] = o0;
        *(float4*)&Si[((long)b * KD + row) * SS + n0 + 64 + tx * 4] = o1;
    }
}

// ---------- ci = a_ik @ e_i  (64x128 tiles, grid (16,3,BB)) ----------
__global__ __launch_bounds__(256, 2)
void k_ci64m(const float* __restrict__ Aik, const float* __restrict__ E, float* __restrict__ Ci) {
    __shared__ float As[16][68];
    __shared__ float Bs[16][132];
    int b = blockIdx.z;
    int m0 = blockIdx.x * 64;
    int n0 = blockIdx.y * 128;
    const float* Ab = Aik + (long)b * KD * KD;
    const float* Eb = E + (long)b * KD * SS;
    int t = threadIdx.x, ty = t >> 4, tx = t & 15;
    int la_r = t / 4, la_c = (t % 4) * 4;
    int lb_r = t >> 4, lb_c = (t & 15) * 4;
    float acc[4][8] = {};
    for (int k0 = 0; k0 < KD; k0 += 16) {
        float4 a0 = *(const float4*)&Ab[(long)(m0 + la_r) * KD + k0 + la_c];
        float4 b0 = *(const float4*)&Eb[(long)(k0 + lb_r) * SS + n0 + lb_c];
        float4 b1 = *(const float4*)&Eb[(long)(k0 + lb_r) * SS + n0 + 64 + lb_c];
        __syncthreads();
        storeA_t64(As, a0, la_r, la_c);
        *(float4*)&Bs[lb_r][lb_c] = b0;
        *(float4*)&Bs[lb_r][64 + lb_c] = b1;
        __syncthreads();
        mac16m(acc, As, Bs, ty, tx);
    }
#pragma unroll
    for (int i = 0; i < 4; i++) {
        int row = m0 + ty * 4 + i;
        *(float4*)&Ci[((long)b * KD + row) * SS + n0 + tx * 4] = *(float4*)&acc[i][0];
        *(float4*)&Ci[((long)b * KD + row) * SS + n0 + 64 + tx * 4] = *(float4*)&acc[i][4];
    }
}

// ---------- r_i = tanh([e,si,ci] @ Wr + br)  (64x128 tiles, grid (256,3)) ----------
__global__ __launch_bounds__(256, 2)
void k_ri64m(const float* __restrict__ E, const float* __restrict__ Si, const float* __restrict__ Ci,
             const float* __restrict__ Wr, const float* __restrict__ br, float* __restrict__ out) {
    __shared__ float As[16][68];
    __shared__ float Bs[16][132];
    int m0 = blockIdx.x * 64, n0 = blockIdx.y * 128;
    int t = threadIdx.x, ty = t >> 4, tx = t & 15;
    int la_r = t / 4, la_c = (t % 4) * 4;
    int lb_r = t >> 4, lb_c = (t & 15) * 4;
    float acc[4][8] = {};
    const float* srcs[3] = {E, Si, Ci};
    for (int seg = 0; seg < 3; seg++) {
        const float* Sp = srcs[seg];
        for (int k0 = 0; k0 < SS; k0 += 16) {
            float4 a0 = *(const float4*)&Sp[(long)(m0 + la_r) * SS + k0 + la_c];
            float4 b0 = *(const float4*)&Wr[(long)(seg * SS + k0 + lb_r) * SS + n0 + lb_c];
            float4 b1 = *(const float4*)&Wr[(long)(seg * SS + k0 + lb_r) * SS + n0 + 64 + lb_c];
            __syncthreads();
            storeA_t64(As, a0, la_r, la_c);
            *(float4*)&Bs[lb_r][lb_c] = b0;
            *(float4*)&Bs[lb_r][64 + lb_c] = b1;
            __syncthreads();
            mac16m(acc, As, Bs, ty, tx);
        }
    }
#pragma unroll
    for (int i = 0; i < 4; i++) {
        int row = m0 + ty * 4 + i;
        float4 o0, o1;
        float* p0 = &o0.x; float* p1 = &o1.x;
#pragma unroll
        for (int j = 0; j < 4; j++) {
            p0[j] = tanhf(acc[i][j] + br[n0 + tx * 4 + j]);
            p1[j] = tanhf(acc[i][j + 4] + br[n0 + 64 + tx * 4 + j]);
        }
        *(float4*)&out[(long)row * SS + n0 + tx * 4] = o0;
        *(float4*)&out[(long)row * SS + n0 + 64 + tx * 4] = o1;
    }
}

extern "C" void kernel_launch(void* const* d_in, const int* in_sizes, int n_in,
                              void* d_out, int out_size, void* d_ws, size_t ws_size,
                              hipStream_t stream) {
    const float* x     = (const float*)d_in[0];
    const float* Wp_w  = (const float*)d_in[1];
    const float* Wp_b  = (const float*)d_in[2];
    const float* Wc_w  = (const float*)d_in[3];
    const float* Wc_b  = (const float*)d_in[4];
    const float* fi_w  = (const float*)d_in[5];
    const float* Wa_w  = (const float*)d_in[6];
    const float* expar = (const float*)d_in[7];
    const float* Wr_w  = (const float*)d_in[8];
    const float* Wr_b  = (const float*)d_in[9];

    float* ws = (float*)d_ws;
    // Region R (offset 23,068,672, span 33,554,432 f32 = 128 MB) is time-multiplexed:
    // early {di/tt, uj, uk}; mid: Td (fp64 padded T matrix -> Tinv); late: {si, ci}.
    float*  A    = ws;                               // 16,777,216 f32 (S -> A -> a_ik)
    float*  ei   = ws + 16777216;                    //  6,291,456 f32
    float*  R    = ws + 23068672;
    float*  di   = R;
    float*  uj   = R + 6291456;
    float*  uk   = R + 12582912;
    float*  tt   = di;
    double* Td   = (double*)R;                       // 16,777,216 doubles = 128 MB
    float*  sbuf = R;                                // after Td dead
    float*  cbuf = R + 6291456;
    double* Ftd  = (double*)(ws + 56623104);         // 1,048,576 doubles = 8 MB
    float*  g    = ws + 58720256;                    // 16,384
    float*  mcol = ws + 58736640;                    // 16,384
    float*  fi   = ws + 58753024;                    // 16,384
    float*  d0   = ws + 58769408;                    // 16,384
    double* csd  = (double*)(ws + 58785792);         // 16,384 doubles
    double* wd   = (double*)(ws + 58818560);         // 16,384 doubles
    double* vd   = (double*)(ws + 58851328);         // 16,384 doubles
    double* dgvd = (double*)(ws + 58884096);         // 16,384 doubles
    double* a0c  = (double*)(ws + 58916864);         // 16,384 doubles
    double* frc  = (double*)(ws + 58949632);         // 16,384 doubles
    double* sd   = (double*)(ws + 58982400);         // 16 doubles; end ~236 MB

    float* r_out   = (float*)d_out;
    float* aki_out = r_out + (long)BB * KD * SS;
    // aki output region (64 MB) is dead until k_aki: borrow 1 MB as colmax scratch.
    float* pmax    = aki_out;                        // 16 * 16384 f32

    k_prep<<<BB * KD * SS / 256, 256, 0, stream>>>(x, di, ei);
    k_gemm_pc<<<dim3(128, 6), 256, 0, stream>>>(di, Wp_w, Wp_b, Wc_w, Wc_b, uj, uk);
    k_firaw<<<BB * KD / 4, 256, 0, stream>>>(di, fi_w, g);
    k_gemm64m<false, false><<<dim3(256, 3), 256, 0, stream>>>(uj, Wa_w, nullptr, tt, BB * KD, SS, SS);
    k_fjk16<<<dim3(8, 8, BB), 256, 0, stream>>>(tt, uk, A);
    k_colmax1<<<dim3(BB * KD / 256, 16), 256, 0, stream>>>(A, pmax);
    k_colmax2<<<BB * KD / 256, 256, 0, stream>>>(pmax, g, mcol, fi, csd);
    k_expA_sum<<<dim3(16, 16, BB), 256, 0, stream>>>(A, mcol, csd);
    k_buildT<<<BB * KD * KD / 256, 256, 0, stream>>>(A, csd, Td);

    for (int s = 0; s < KD / NBLK; s++) {
        int kb = s * NBLK;
        k_diagsave_d<<<BB * KD * NBLK / 256 + BB, 256, 0, stream>>>(Td, Ftd, kb);
        k_rowcol_d<<<dim3((KD - NBLK) / 32, BB), 256, 0, stream>>>(Td, kb);
        k_elim_d<<<dim3(8, 16, BB), 256, 0, stream>>>(Td, Ftd, kb);
    }

    k_compact<<<BB * KD / 256, 256, 0, stream>>>(A, fi, a0c, frc, vd);
    k_w<<<BB * KD / 4, 256, 0, stream>>>(Td, a0c, wd);
    k_s2<<<BB, 256, 0, stream>>>(wd, frc, fi, sd);
    k_v<<<dim3(4, 8, BB), 256, 0, stream>>>(Td, frc, vd);
    k_dgv<<<BB * KD / 256, 256, 0, stream>>>(Td, wd, vd, sd, fi, dgvd, d0);
    k_aik2<<<dim3(16, 16, BB), 256, 0, stream>>>(A, Td, wd, vd, dgvd, sd);
    k_aki<<<dim3(16, 16, BB), 256, 0, stream>>>(A, d0, aki_out);
    k_si64m<<<dim3(16, 3, BB), 256, 0, stream>>>(A, ei, d0, expar, sbuf);
    k_ci64m<<<dim3(16, 3, BB), 256, 0, stream>>>(A, ei, cbuf);
    k_ri64m<<<dim3(256, 3), 256, 0, stream>>>(ei, sbuf, cbuf, Wr_w, Wr_b, r_out);
}